// Round 1
// baseline (35407.858 us; speedup 1.0000x reference)
//
#include <hip/hip_runtime.h>
#include <stdint.h>
#include <math.h>

// ---------------------------------------------------------------------------
// ConditionalAttackModule: 126-step LSTM history scan + 100x20-step stochastic
// LSTM rollout with importance weights, B=8192, H=128.
//
// Round 0 design notes:
//  * fp32 VALU everywhere (no fp32 MFMA on CDNA4). Compute-bound, ~14 ms floor.
//  * RNG must be bit-exact vs jax.random (threefry2x32). Two key-derivation
//    schemes exist; modern JAX defaults to "partitionable". Toggle below.
//  * Persistent workgroups: 256 thr / 64 rows, h transposed in LDS, c in regs,
//    W_hh staged via LDS 8-k blocks. MC phase needs no global h/c traffic.
// ---------------------------------------------------------------------------

#define PARTITIONABLE 1   // 1 = modern JAX (jax_threefry_partitionable=True)

#define HH     128
#define NG     512
#define NB     8192
#define NSAMP  100
#define NSTEP  20
#define TCAP   18      // xs index captured (STEP_PRED-1)
#define NHIST  126     // scan over returns[:-1]
#define NRET   127

// ----------------------------- threefry2x32 --------------------------------
__device__ __forceinline__ void tf2x32(uint32_t k0, uint32_t k1,
                                       uint32_t x0, uint32_t x1,
                                       uint32_t &y0, uint32_t &y1) {
  uint32_t ks2 = k0 ^ k1 ^ 0x1BD11BDAu;
  x0 += k0; x1 += k1;
#define RR(r) { x0 += x1; x1 = (x1 << (r)) | (x1 >> (32 - (r))); x1 ^= x0; }
  RR(13) RR(15) RR(26) RR(6)   x0 += k1;  x1 += ks2 + 1u;
  RR(17) RR(29) RR(16) RR(24)  x0 += ks2; x1 += k0  + 2u;
  RR(13) RR(15) RR(26) RR(6)   x0 += k0;  x1 += k1  + 3u;
  RR(17) RR(29) RR(16) RR(24)  x0 += k1;  x1 += ks2 + 4u;
  RR(13) RR(15) RR(26) RR(6)   x0 += ks2; x1 += k0  + 5u;
#undef RR
  y0 = x0; y1 = x1;
}

// XLA ErfInv f32 (Giles polynomial) — matches CPU reference to ~1 ulp.
__device__ __forceinline__ float erfinv32(float x) {
  float w = -log1pf(-x * x);
  float p;
  if (w < 5.0f) {
    w = w - 2.5f;
    p = 2.81022636e-08f;
    p = fmaf(p, w, 3.43273939e-07f);
    p = fmaf(p, w, -3.5233877e-06f);
    p = fmaf(p, w, -4.39150654e-06f);
    p = fmaf(p, w, 0.00021858087f);
    p = fmaf(p, w, -0.00125372503f);
    p = fmaf(p, w, -0.00417768164f);
    p = fmaf(p, w, 0.246640727f);
    p = fmaf(p, w, 1.50140941f);
  } else {
    w = sqrtf(w) - 3.0f;
    p = -0.000200214257f;
    p = fmaf(p, w, 0.000100950558f);
    p = fmaf(p, w, 0.00134934322f);
    p = fmaf(p, w, -0.00367342844f);
    p = fmaf(p, w, 0.00573950773f);
    p = fmaf(p, w, -0.0076224613f);
    p = fmaf(p, w, 0.00943887047f);
    p = fmaf(p, w, 1.00167406f);
    p = fmaf(p, w, 2.83297682f);
  }
  return p * x;
}

// jax.random.normal(key, (8192,), f32) element idx
__device__ __forceinline__ float normal32(uint32_t k0, uint32_t k1, uint32_t idx) {
  uint32_t bits;
#if PARTITIONABLE
  uint32_t y0, y1;
  tf2x32(k0, k1, 0u, idx, y0, y1);
  bits = y0 ^ y1;
#else
  uint32_t y0, y1;
  if (idx < 4096u) { tf2x32(k0, k1, idx, idx + 4096u, y0, y1); bits = y0; }
  else             { tf2x32(k0, k1, idx - 4096u, idx, y0, y1); bits = y1; }
#endif
  float f = __uint_as_float((bits >> 9) | 0x3f800000u) - 1.0f;   // [0,1)
  const float lo = __uint_as_float(0xBF7FFFFFu);                 // nextafter(-1,0)
  float u = fmaxf(lo, f * 2.0f + lo);   // (hi-lo) rounds to exactly 2.0f in f32
  return 1.41421356f * erfinv32(u);
}

__device__ __forceinline__ float sigmoidf(float x) {
  return 1.0f / (1.0f + expf(-x));
}

// ------------------------------- small kernels -----------------------------
__global__ void returns_kernel(const float* __restrict__ inp,
                               const float* __restrict__ pert,
                               float* __restrict__ ret) {
  int i = blockIdx.x * blockDim.x + threadIdx.x;
  if (i >= NRET * NB) return;
  int s = i / NB, b = i - s * NB;
  float p0 = inp[s * NB + b] * (1.0f + pert[s * NB + b]);
  float p1 = inp[(s + 1) * NB + b] * (1.0f + pert[(s + 1) * NB + b]);
  ret[i] = p1 - p0;
}

// step keys: keys[s*20+t] = split(split(key(42),100)[s], 20)[t]
__global__ void keys_kernel(uint32_t* __restrict__ keys) {
  int id = blockIdx.x * blockDim.x + threadIdx.x;
  if (id >= NSAMP * NSTEP) return;
  int s = id / NSTEP, t = id - s * NSTEP;
  uint32_t sk0, sk1, k0, k1;
#if PARTITIONABLE
  tf2x32(0u, 42u, 0u, (uint32_t)s, sk0, sk1);
  tf2x32(sk0, sk1, 0u, (uint32_t)t, k0, k1);
#else
  uint32_t u0, u1, v0, v1;
  if (s < 50) { tf2x32(0u, 42u, 2*s,     2*s+100, u0, u1);
                tf2x32(0u, 42u, 2*s+1,   2*s+101, v0, v1); sk0 = u0; sk1 = v0; }
  else        { tf2x32(0u, 42u, 2*s-100, 2*s,     u0, u1);
                tf2x32(0u, 42u, 2*s-99,  2*s+1,   v0, v1); sk0 = u1; sk1 = v1; }
  if (t < 10) { tf2x32(sk0, sk1, 2*t,    2*t+20,  u0, u1);
                tf2x32(sk0, sk1, 2*t+1,  2*t+21,  v0, v1); k0 = u0; k1 = v0; }
  else        { tf2x32(sk0, sk1, 2*t-20, 2*t,     u0, u1);
                tf2x32(sk0, sk1, 2*t-19, 2*t+1,   v0, v1); k0 = u1; k1 = v1; }
#endif
  keys[2 * id] = k0; keys[2 * id + 1] = k1;
}

// ------------------------ LSTM tile core (shared idiom) --------------------
// Workgroup: 256 threads = (tr 0..7) x (tc 0..31); 64 rows.
// Thread tile: rows 8*tr..+7, hidden units 4*tc..+3, all 4 gates.
// h_t[k][row] in LDS (b128 row fragments), c in regs, acc = 128 VGPRs.

#define GATE_STEP_BODY(X_EXPR)                                                 \
  float acc[8][4][4];                                                          \
  {                                                                            \
    float wih[4][4], bb[4][4];                                                 \
    _Pragma("unroll")                                                          \
    for (int g = 0; g < 4; ++g) {                                              \
      float4 wv = *(const float4*)&wih_s[g * 128 + 4 * tc];                    \
      float4 bv = *(const float4*)&b_s[g * 128 + 4 * tc];                      \
      wih[g][0] = wv.x; wih[g][1] = wv.y; wih[g][2] = wv.z; wih[g][3] = wv.w;  \
      bb[g][0] = bv.x; bb[g][1] = bv.y; bb[g][2] = bv.z; bb[g][3] = bv.w;      \
    }                                                                          \
    _Pragma("unroll")                                                          \
    for (int r = 0; r < 8; ++r) {                                              \
      float xr = (X_EXPR);                                                     \
      _Pragma("unroll")                                                        \
      for (int g = 0; g < 4; ++g)                                              \
        _Pragma("unroll")                                                      \
        for (int j = 0; j < 4; ++j)                                            \
          acc[r][g][j] = fmaf(xr, wih[g][j], bb[g][j]);                        \
    }                                                                          \
  }                                                                            \
  for (int kb = 0; kb < 16; ++kb) {                                            \
    if (kb) __syncthreads();                                                   \
    {                                                                          \
      const float4* src = (const float4*)(W_hh + kb * 8 * NG);                 \
      float4* dst = (float4*)w_s;                                              \
      _Pragma("unroll")                                                        \
      for (int m = 0; m < 4; ++m) dst[tid + 256 * m] = src[tid + 256 * m];     \
    }                                                                          \
    __syncthreads();                                                           \
    _Pragma("unroll")                                                          \
    for (int kk = 0; kk < 8; ++kk) {                                           \
      const int k = kb * 8 + kk;                                               \
      float4 ha = *(const float4*)&h_t[k * 64 + 8 * tr];                       \
      float4 hb = *(const float4*)&h_t[k * 64 + 8 * tr + 4];                   \
      float hv[8] = {ha.x, ha.y, ha.z, ha.w, hb.x, hb.y, hb.z, hb.w};          \
      float wv[4][4];                                                          \
      _Pragma("unroll")                                                        \
      for (int g = 0; g < 4; ++g) {                                            \
        float4 w4 = *(const float4*)&w_s[kk * NG + g * 128 + 4 * tc];          \
        wv[g][0] = w4.x; wv[g][1] = w4.y; wv[g][2] = w4.z; wv[g][3] = w4.w;    \
      }                                                                        \
      _Pragma("unroll")                                                        \
      for (int r = 0; r < 8; ++r)                                              \
        _Pragma("unroll")                                                      \
        for (int g = 0; g < 4; ++g)                                            \
          _Pragma("unroll")                                                    \
          for (int j = 0; j < 4; ++j)                                          \
            acc[r][g][j] = fmaf(hv[r], wv[g][j], acc[r][g][j]);                \
    }                                                                          \
  }                                                                            \
  __syncthreads(); /* all h_t reads done before epilogue overwrites h_t */     \
  _Pragma("unroll")                                                            \
  for (int r = 0; r < 8; ++r) {                                                \
    _Pragma("unroll")                                                          \
    for (int j = 0; j < 4; ++j) {                                              \
      float ig = sigmoidf(acc[r][0][j]);                                       \
      float fg = sigmoidf(acc[r][1][j]);                                       \
      float gg = tanhf(acc[r][2][j]);                                          \
      float og = sigmoidf(acc[r][3][j]);                                       \
      float c = fmaf(fg, c_reg[r][j], ig * gg);                                \
      c_reg[r][j] = c;                                                         \
      h_t[(4 * tc + j) * 64 + 8 * tr + r] = og * tanhf(c);                     \
    }                                                                          \
  }

// ------------------------------ history kernel -----------------------------
__launch_bounds__(256, 2)
__global__ void hist_kernel(const float* __restrict__ ret,
                            const float* __restrict__ W_ih,
                            const float* __restrict__ W_hh,
                            const float* __restrict__ bias,
                            float* __restrict__ hout,
                            float* __restrict__ cout) {
  __shared__ float h_t[HH * 64];
  __shared__ float w_s[8 * NG];
  __shared__ float x_s[64];
  __shared__ float wih_s[NG];
  __shared__ float b_s[NG];

  const int tid = threadIdx.x;
  const int tc = tid & 31, tr = tid >> 5;
  const int b0 = blockIdx.x * 64;

  for (int i = tid; i < HH * 64; i += 256) h_t[i] = 0.0f;
  for (int i = tid; i < NG; i += 256) { wih_s[i] = W_ih[i]; b_s[i] = bias[i]; }

  float c_reg[8][4];
#pragma unroll
  for (int r = 0; r < 8; ++r)
#pragma unroll
    for (int j = 0; j < 4; ++j) c_reg[r][j] = 0.0f;

  for (int t = 0; t < NHIST; ++t) {
    if (tid < 64) x_s[tid] = ret[t * NB + b0 + tid];
    __syncthreads();  // x_s ready; previous h_t writes visible; w_s free
    GATE_STEP_BODY(x_s[8 * tr + r])
    __syncthreads();  // h_t(new) visible for next iteration
  }

#pragma unroll
  for (int r = 0; r < 8; ++r) {
    int row = b0 + 8 * tr + r;
    float4 hv = make_float4(h_t[(4 * tc + 0) * 64 + 8 * tr + r],
                            h_t[(4 * tc + 1) * 64 + 8 * tr + r],
                            h_t[(4 * tc + 2) * 64 + 8 * tr + r],
                            h_t[(4 * tc + 3) * 64 + 8 * tr + r]);
    *(float4*)&hout[row * HH + 4 * tc] = hv;
    *(float4*)&cout[row * HH + 4 * tc] =
        make_float4(c_reg[r][0], c_reg[r][1], c_reg[r][2], c_reg[r][3]);
  }
}

// -------------------------------- MC kernel --------------------------------
__launch_bounds__(256, 2)
__global__ void mc_kernel(const float* __restrict__ ret,
                          const float* __restrict__ hin,
                          const float* __restrict__ cin,
                          const float* __restrict__ W_ih,
                          const float* __restrict__ W_hh,
                          const float* __restrict__ bias,
                          const float* __restrict__ w_mu,
                          const float* __restrict__ b_mu,
                          const float* __restrict__ w_ls,
                          const float* __restrict__ b_ls,
                          const uint32_t* __restrict__ keys,
                          float* __restrict__ accum) {
  __shared__ float h_t[HH * 64];
  __shared__ float w_s[8 * NG];
  __shared__ float x_s[64];
  __shared__ float wih_s[NG];
  __shared__ float b_s[NG];
  __shared__ float wmu_s[HH];
  __shared__ float wls_s[HH];

  const int tid = threadIdx.x;
  const int tc = tid & 31, tr = tid >> 5;
  const int s = blockIdx.x >> 7;          // sample
  const int b0 = (blockIdx.x & 127) * 64; // row block within batch

  for (int i = tid; i < NG; i += 256) { wih_s[i] = W_ih[i]; b_s[i] = bias[i]; }
  if (tid < HH) { wmu_s[tid] = w_mu[tid]; wls_s[tid] = w_ls[tid]; }

  float c_reg[8][4];
#pragma unroll
  for (int r = 0; r < 8; ++r) {
    int row = b0 + 8 * tr + r;
    float4 cv = *(const float4*)&cin[row * HH + 4 * tc];
    c_reg[r][0] = cv.x; c_reg[r][1] = cv.y; c_reg[r][2] = cv.z; c_reg[r][3] = cv.w;
    float4 hv = *(const float4*)&hin[row * HH + 4 * tc];
    h_t[(4 * tc + 0) * 64 + 8 * tr + r] = hv.x;
    h_t[(4 * tc + 1) * 64 + 8 * tr + r] = hv.y;
    h_t[(4 * tc + 2) * 64 + 8 * tr + r] = hv.z;
    h_t[(4 * tc + 3) * 64 + 8 * tr + r] = hv.w;
  }
  if (tid < 64) x_s[tid] = ret[126 * NB + b0 + tid];  // last = returns[-1]

  float logw = 0.0f, outv = 0.0f;
  const float bmu = b_mu[0], bls = b_ls[0];

  __syncthreads();

  for (int t = 0; t < NSTEP; ++t) {
    GATE_STEP_BODY(x_s[8 * tr + r])
    __syncthreads();  // new h_t visible to the mu/sigma wave
    if (tid < 64) {
      const int r = tid;
      float mu = 0.0f, ls = 0.0f;
      for (int k = 0; k < HH; ++k) {
        float hv = h_t[k * 64 + r];
        mu = fmaf(hv, wmu_s[k], mu);
        ls = fmaf(hv, wls_s[k], ls);
      }
      mu += bmu; ls += bls;
      float sg = expf(fminf(fmaxf(ls, -5.0f), 2.0f));
      uint32_t k0 = keys[2 * (s * NSTEP + t)];
      uint32_t k1 = keys[2 * (s * NSTEP + t) + 1];
      float z = normal32(k0, k1, (uint32_t)(b0 + r));
      float xn = mu + sg * (z + 0.5f);
      logw -= fmaf(0.5f, z, 0.125f);
      if (t == TCAP) outv = xn;
      x_s[r] = xn;
    }
    __syncthreads();  // x_s(new) visible before next gate phase
  }

  if (tid < 64) {
    float w = expf(logw);
    float ow = outv * w;
    int b = b0 + tid;
    atomicAdd(&accum[0 * NB + b], w);
    atomicAdd(&accum[1 * NB + b], ow);
    atomicAdd(&accum[2 * NB + b], w * w);
    atomicAdd(&accum[3 * NB + b], ow * ow);
    atomicAdd(&accum[4 * NB + b], outv * w * w);
  }
}

// ------------------------------- final kernel ------------------------------
__global__ void final_kernel(const float* __restrict__ accum,
                             float* __restrict__ out) {
  int b = blockIdx.x * blockDim.x + threadIdx.x;
  if (b >= NB) return;
  float sw = accum[0 * NB + b];
  float sm1 = accum[1 * NB + b];
  float sqw = accum[2 * NB + b];
  float sm2 = accum[3 * NB + b];
  float shm = accum[4 * NB + b];
  float mean = sm1 / sw;
  float sem = sm2 + sqw * mean * mean - 2.0f * shm * mean;
  sem = sqrtf(sem / (float)(NSAMP * (NSAMP - 1)));
  out[b] = mean;
  out[NB + b] = sem;
}

// ------------------------------- launcher ----------------------------------
extern "C" void kernel_launch(void* const* d_in, const int* in_sizes, int n_in,
                              void* d_out, int out_size, void* d_ws, size_t ws_size,
                              hipStream_t stream) {
  (void)in_sizes; (void)n_in; (void)out_size; (void)ws_size;
  const float* inp  = (const float*)d_in[0];
  const float* pert = (const float*)d_in[1];
  const float* W_ih = (const float*)d_in[2];
  const float* W_hh = (const float*)d_in[3];
  const float* bias = (const float*)d_in[4];
  const float* w_mu = (const float*)d_in[5];
  const float* b_mu = (const float*)d_in[6];
  const float* w_ls = (const float*)d_in[7];
  const float* b_ls = (const float*)d_in[8];

  char* ws = (char*)d_ws;
  float* ret = (float*)ws;        ws += (size_t)NRET * NB * sizeof(float);
  float* hh  = (float*)ws;        ws += (size_t)NB * HH * sizeof(float);
  float* cc  = (float*)ws;        ws += (size_t)NB * HH * sizeof(float);
  uint32_t* keys = (uint32_t*)ws; ws += (size_t)NSAMP * NSTEP * 2 * sizeof(uint32_t);
  float* accum = (float*)ws;      // 5 * NB floats

  hipMemsetAsync(accum, 0, (size_t)5 * NB * sizeof(float), stream);
  returns_kernel<<<(NRET * NB + 255) / 256, 256, 0, stream>>>(inp, pert, ret);
  keys_kernel<<<(NSAMP * NSTEP + 255) / 256, 256, 0, stream>>>(keys);
  hist_kernel<<<NB / 64, 256, 0, stream>>>(ret, W_ih, W_hh, bias, hh, cc);
  mc_kernel<<<NSAMP * (NB / 64), 256, 0, stream>>>(ret, hh, cc, W_ih, W_hh, bias,
                                                   w_mu, b_mu, w_ls, b_ls, keys, accum);
  final_kernel<<<NB / 256 + (NB % 256 != 0), 256, 0, stream>>>(accum, (float*)d_out);
}

// Round 2
// 31151.996 us; speedup vs baseline: 1.1366x; 1.1366x over previous
//
#include <hip/hip_runtime.h>
#include <stdint.h>
#include <math.h>

// ---------------------------------------------------------------------------
// ConditionalAttackModule: 126-step LSTM history scan + 100x20-step stochastic
// LSTM rollout with importance weights, B=8192, H=128.
//
// Round 2:
//  * h_t row-major [row][128]: float4 epilogue writes (conflict-free) +
//    broadcast float4 gate reads. Kills the 2.05e9 bank-conflict cycles.
//  * mu/sigma computed from epilogue registers + __shfl_xor butterfly;
//    serial 64-thread phase removed.
//  * __expf/v_rcp based sigmoid/tanh (abs err ~1e-7, threshold 9.6e-3).
//  * hist kernel: 32-row blocks -> 256 blocks (was 128 on 256 CUs).
// ---------------------------------------------------------------------------

#define HH     128
#define NG     512
#define NB     8192
#define NSAMP  100
#define NSTEP  20
#define TCAP   18      // xs index captured (STEP_PRED-1)
#define NHIST  126
#define NRET   127

// ----------------------------- threefry2x32 --------------------------------
__device__ __forceinline__ void tf2x32(uint32_t k0, uint32_t k1,
                                       uint32_t x0, uint32_t x1,
                                       uint32_t &y0, uint32_t &y1) {
  uint32_t ks2 = k0 ^ k1 ^ 0x1BD11BDAu;
  x0 += k0; x1 += k1;
#define RR(r) { x0 += x1; x1 = (x1 << (r)) | (x1 >> (32 - (r))); x1 ^= x0; }
  RR(13) RR(15) RR(26) RR(6)   x0 += k1;  x1 += ks2 + 1u;
  RR(17) RR(29) RR(16) RR(24)  x0 += ks2; x1 += k0  + 2u;
  RR(13) RR(15) RR(26) RR(6)   x0 += k0;  x1 += k1  + 3u;
  RR(17) RR(29) RR(16) RR(24)  x0 += k1;  x1 += ks2 + 4u;
  RR(13) RR(15) RR(26) RR(6)   x0 += ks2; x1 += k0  + 5u;
#undef RR
  y0 = x0; y1 = x1;
}

// XLA ErfInv f32 (Giles polynomial)
__device__ __forceinline__ float erfinv32(float x) {
  float w = -log1pf(-x * x);
  float p;
  if (w < 5.0f) {
    w = w - 2.5f;
    p = 2.81022636e-08f;
    p = fmaf(p, w, 3.43273939e-07f);
    p = fmaf(p, w, -3.5233877e-06f);
    p = fmaf(p, w, -4.39150654e-06f);
    p = fmaf(p, w, 0.00021858087f);
    p = fmaf(p, w, -0.00125372503f);
    p = fmaf(p, w, -0.00417768164f);
    p = fmaf(p, w, 0.246640727f);
    p = fmaf(p, w, 1.50140941f);
  } else {
    w = sqrtf(w) - 3.0f;
    p = -0.000200214257f;
    p = fmaf(p, w, 0.000100950558f);
    p = fmaf(p, w, 0.00134934322f);
    p = fmaf(p, w, -0.00367342844f);
    p = fmaf(p, w, 0.00573950773f);
    p = fmaf(p, w, -0.0076224613f);
    p = fmaf(p, w, 0.00943887047f);
    p = fmaf(p, w, 1.00167406f);
    p = fmaf(p, w, 2.83297682f);
  }
  return p * x;
}

// jax.random.normal(key, (8192,), f32) element idx — partitionable threefry
__device__ __forceinline__ float normal32(uint32_t k0, uint32_t k1, uint32_t idx) {
  uint32_t y0, y1;
  tf2x32(k0, k1, 0u, idx, y0, y1);
  uint32_t bits = y0 ^ y1;
  float f = __uint_as_float((bits >> 9) | 0x3f800000u) - 1.0f;   // [0,1)
  const float lo = __uint_as_float(0xBF7FFFFFu);                 // nextafter(-1,0)
  float u = fmaxf(lo, f * 2.0f + lo);
  return 1.41421356f * erfinv32(u);
}

// fast transcendentals: v_exp_f32 + v_rcp_f32 (abs err ~1e-7)
__device__ __forceinline__ float fast_sigmoid(float x) {
  return __builtin_amdgcn_rcpf(1.0f + __expf(-x));
}
__device__ __forceinline__ float fast_tanh(float x) {
  // 1 - 2/(1+exp(2x)); saturates correctly at +/-inf exp values
  return 1.0f - 2.0f * __builtin_amdgcn_rcpf(1.0f + __expf(2.0f * x));
}

// ------------------------------- small kernels -----------------------------
__global__ void returns_kernel(const float* __restrict__ inp,
                               const float* __restrict__ pert,
                               float* __restrict__ ret) {
  int i = blockIdx.x * blockDim.x + threadIdx.x;
  if (i >= NRET * NB) return;
  int s = i / NB, b = i - s * NB;
  float p0 = inp[s * NB + b] * (1.0f + pert[s * NB + b]);
  float p1 = inp[(s + 1) * NB + b] * (1.0f + pert[(s + 1) * NB + b]);
  ret[i] = p1 - p0;
}

__global__ void keys_kernel(uint32_t* __restrict__ keys) {
  int id = blockIdx.x * blockDim.x + threadIdx.x;
  if (id >= NSAMP * NSTEP) return;
  int s = id / NSTEP, t = id - s * NSTEP;
  uint32_t sk0, sk1, k0, k1;
  tf2x32(0u, 42u, 0u, (uint32_t)s, sk0, sk1);
  tf2x32(sk0, sk1, 0u, (uint32_t)t, k0, k1);
  keys[2 * id] = k0; keys[2 * id + 1] = k1;
}

// ------------------------ LSTM tile core (templated) -----------------------
// 256 threads = (tr 0..7) x (tc 0..31); block rows = 8*RT; thread tile:
// rows RT*tr..+RT-1, hidden cols 4*tc..+3, all 4 gates.
// h_t row-major [row][HH]: gate reads are broadcast float4 (free);
// epilogue writes are lane-consecutive float4 (conflict-free).

template<int RT>
__device__ __forceinline__ void acc_init(float (&acc)[RT][4][4],
                                         const float* __restrict__ wihb_s,
                                         const float (&xr)[RT], int tc) {
  float wih[4][4], bb[4][4];
#pragma unroll
  for (int g = 0; g < 4; ++g) {
    float4 wv = *(const float4*)&wihb_s[g * 128 + 4 * tc];
    float4 bv = *(const float4*)&wihb_s[NG + g * 128 + 4 * tc];
    wih[g][0] = wv.x; wih[g][1] = wv.y; wih[g][2] = wv.z; wih[g][3] = wv.w;
    bb[g][0] = bv.x; bb[g][1] = bv.y; bb[g][2] = bv.z; bb[g][3] = bv.w;
  }
#pragma unroll
  for (int r = 0; r < RT; ++r)
#pragma unroll
    for (int g = 0; g < 4; ++g)
#pragma unroll
      for (int j = 0; j < 4; ++j)
        acc[r][g][j] = fmaf(xr[r], wih[g][j], bb[g][j]);
}

template<int RT>
__device__ __forceinline__ void gate_matmul(float (&acc)[RT][4][4],
                                            const float* __restrict__ W_hh,
                                            const float* __restrict__ h_t,
                                            float* __restrict__ w_s,
                                            int tid, int tc, int tr) {
  for (int kb = 0; kb < 16; ++kb) {
    if (kb) __syncthreads();
    {
      const float4* src = (const float4*)(W_hh + kb * 8 * NG);
      float4* dst = (float4*)w_s;
#pragma unroll
      for (int m = 0; m < 4; ++m) dst[tid + 256 * m] = src[tid + 256 * m];
    }
    __syncthreads();
#pragma unroll
    for (int g4 = 0; g4 < 2; ++g4) {
      float h4[RT][4];
#pragma unroll
      for (int r = 0; r < RT; ++r) {
        float4 tv = *(const float4*)&h_t[(RT * tr + r) * HH + kb * 8 + g4 * 4];
        h4[r][0] = tv.x; h4[r][1] = tv.y; h4[r][2] = tv.z; h4[r][3] = tv.w;
      }
#pragma unroll
      for (int q = 0; q < 4; ++q) {
        float wv[4][4];
#pragma unroll
        for (int g = 0; g < 4; ++g) {
          float4 w4 = *(const float4*)&w_s[(g4 * 4 + q) * NG + g * 128 + 4 * tc];
          wv[g][0] = w4.x; wv[g][1] = w4.y; wv[g][2] = w4.z; wv[g][3] = w4.w;
        }
#pragma unroll
        for (int r = 0; r < RT; ++r)
#pragma unroll
          for (int g = 0; g < 4; ++g)
#pragma unroll
            for (int j = 0; j < 4; ++j)
              acc[r][g][j] = fmaf(h4[r][q], wv[g][j], acc[r][g][j]);
      }
    }
  }
  __syncthreads();  // all h_t reads done before epilogue overwrites h_t
}

template<int RT>
__device__ __forceinline__ void cell_update(const float (&acc)[RT][4][4],
                                            float (&c_reg)[RT][4],
                                            float (&h_new)[RT][4],
                                            float* __restrict__ h_t,
                                            int tc, int tr) {
#pragma unroll
  for (int r = 0; r < RT; ++r) {
#pragma unroll
    for (int j = 0; j < 4; ++j) {
      float ig = fast_sigmoid(acc[r][0][j]);
      float fg = fast_sigmoid(acc[r][1][j]);
      float gg = fast_tanh(acc[r][2][j]);
      float og = fast_sigmoid(acc[r][3][j]);
      float c = fmaf(fg, c_reg[r][j], ig * gg);
      c_reg[r][j] = c;
      h_new[r][j] = og * fast_tanh(c);
    }
    *(float4*)&h_t[(RT * tr + r) * HH + 4 * tc] =
        make_float4(h_new[r][0], h_new[r][1], h_new[r][2], h_new[r][3]);
  }
}

// ------------------------------ history kernel -----------------------------
// 32 rows/block -> 256 blocks (one per CU).
__launch_bounds__(256, 2)
__global__ void hist_kernel(const float* __restrict__ ret,
                            const float* __restrict__ W_ih,
                            const float* __restrict__ W_hh,
                            const float* __restrict__ bias,
                            float* __restrict__ hout,
                            float* __restrict__ cout) {
  __shared__ float h_t[32 * HH];
  __shared__ float w_s[8 * NG];
  __shared__ float wihb_s[2 * NG];

  const int tid = threadIdx.x;
  const int tc = tid & 31, tr = tid >> 5;
  const int b0 = blockIdx.x * 32;

  for (int i = tid; i < 32 * HH; i += 256) h_t[i] = 0.0f;
  for (int i = tid; i < NG; i += 256) { wihb_s[i] = W_ih[i]; wihb_s[NG + i] = bias[i]; }

  float c_reg[4][4];
#pragma unroll
  for (int r = 0; r < 4; ++r)
#pragma unroll
    for (int j = 0; j < 4; ++j) c_reg[r][j] = 0.0f;

  __syncthreads();

  for (int t = 0; t < NHIST; ++t) {
    float xr[4];
#pragma unroll
    for (int r = 0; r < 4; ++r) xr[r] = ret[t * NB + b0 + 4 * tr + r];
    float acc[4][4][4];
    acc_init<4>(acc, wihb_s, xr, tc);
    gate_matmul<4>(acc, W_hh, h_t, w_s, tid, tc, tr);
    float h_new[4][4];
    cell_update<4>(acc, c_reg, h_new, h_t, tc, tr);
    __syncthreads();
  }

#pragma unroll
  for (int r = 0; r < 4; ++r) {
    int row = b0 + 4 * tr + r;
    *(float4*)&hout[row * HH + 4 * tc] = *(const float4*)&h_t[(4 * tr + r) * HH + 4 * tc];
    *(float4*)&cout[row * HH + 4 * tc] =
        make_float4(c_reg[r][0], c_reg[r][1], c_reg[r][2], c_reg[r][3]);
  }
}

// -------------------------------- MC kernel --------------------------------
__launch_bounds__(256, 2)
__global__ void mc_kernel(const float* __restrict__ ret,
                          const float* __restrict__ hin,
                          const float* __restrict__ cin,
                          const float* __restrict__ W_ih,
                          const float* __restrict__ W_hh,
                          const float* __restrict__ bias,
                          const float* __restrict__ w_mu,
                          const float* __restrict__ b_mu,
                          const float* __restrict__ w_ls,
                          const float* __restrict__ b_ls,
                          const uint32_t* __restrict__ keys,
                          float* __restrict__ accum) {
  __shared__ float h_t[64 * HH];
  __shared__ float w_s[8 * NG];
  __shared__ float wihb_s[2 * NG];
  __shared__ float x_s[64];

  const int tid = threadIdx.x;
  const int tc = tid & 31, tr = tid >> 5;
  const int s = blockIdx.x >> 7;          // sample
  const int b0 = (blockIdx.x & 127) * 64; // row block within batch

  for (int i = tid; i < NG; i += 256) { wihb_s[i] = W_ih[i]; wihb_s[NG + i] = bias[i]; }
  float wmu_r[4], wls_r[4];
#pragma unroll
  for (int j = 0; j < 4; ++j) { wmu_r[j] = w_mu[4 * tc + j]; wls_r[j] = w_ls[4 * tc + j]; }
  const float bmu = b_mu[0], bls = b_ls[0];

  float c_reg[8][4];
#pragma unroll
  for (int r = 0; r < 8; ++r) {
    int row = b0 + 8 * tr + r;
    float4 cv = *(const float4*)&cin[row * HH + 4 * tc];
    c_reg[r][0] = cv.x; c_reg[r][1] = cv.y; c_reg[r][2] = cv.z; c_reg[r][3] = cv.w;
    *(float4*)&h_t[(8 * tr + r) * HH + 4 * tc] = *(const float4*)&hin[row * HH + 4 * tc];
  }
  if (tid < 64) x_s[tid] = ret[126 * NB + b0 + tid];  // last = returns[-1]

  const int rsel = tc & 7;   // row this lane owns for RNG/logw (4 redundant copies)
  float logw = 0.0f, outv = 0.0f;

  __syncthreads();

  for (int t = 0; t < NSTEP; ++t) {
    float xr[8];
#pragma unroll
    for (int r = 0; r < 8; ++r) xr[r] = x_s[8 * tr + r];   // broadcast reads
    float acc[8][4][4];
    acc_init<8>(acc, wihb_s, xr, tc);
    gate_matmul<8>(acc, W_hh, h_t, w_s, tid, tc, tr);
    float h_new[8][4];
    cell_update<8>(acc, c_reg, h_new, h_t, tc, tr);

    // mu/ls partials from registers, butterfly-reduce over the 32 tc lanes
    float pmu[8], pls[8];
#pragma unroll
    for (int r = 0; r < 8; ++r) {
      float m = 0.0f, l = 0.0f;
#pragma unroll
      for (int j = 0; j < 4; ++j) {
        m = fmaf(h_new[r][j], wmu_r[j], m);
        l = fmaf(h_new[r][j], wls_r[j], l);
      }
      pmu[r] = m; pls[r] = l;
    }
#pragma unroll
    for (int off = 16; off >= 1; off >>= 1) {
#pragma unroll
      for (int r = 0; r < 8; ++r) {
        pmu[r] += __shfl_xor(pmu[r], off, 32);
        pls[r] += __shfl_xor(pls[r], off, 32);
      }
    }
    float mu_t = pmu[0], ls_t = pls[0];
#pragma unroll
    for (int r = 1; r < 8; ++r) {
      if (rsel == r) { mu_t = pmu[r]; ls_t = pls[r]; }
    }
    float mu = mu_t + bmu;
    float lsc = fminf(fmaxf(ls_t + bls, -5.0f), 2.0f);
    float sg = __expf(lsc);
    uint32_t k0 = keys[2 * (s * NSTEP + t)];
    uint32_t k1 = keys[2 * (s * NSTEP + t) + 1];
    float z = normal32(k0, k1, (uint32_t)(b0 + 8 * tr + rsel));
    float xn = fmaf(sg, z + 0.5f, mu);
    logw -= fmaf(0.5f, z, 0.125f);
    if (t == TCAP) outv = xn;
    if (tc < 8) x_s[8 * tr + tc] = xn;
    __syncthreads();   // x_s + h_t visible for next step
  }

  if (tc < 8) {
    float w = __expf(logw);
    float ow = outv * w;
    int b = b0 + 8 * tr + tc;
    atomicAdd(&accum[0 * NB + b], w);
    atomicAdd(&accum[1 * NB + b], ow);
    atomicAdd(&accum[2 * NB + b], w * w);
    atomicAdd(&accum[3 * NB + b], ow * ow);
    atomicAdd(&accum[4 * NB + b], outv * w * w);
  }
}

// ------------------------------- final kernel ------------------------------
__global__ void final_kernel(const float* __restrict__ accum,
                             float* __restrict__ out) {
  int b = blockIdx.x * blockDim.x + threadIdx.x;
  if (b >= NB) return;
  float sw = accum[0 * NB + b];
  float sm1 = accum[1 * NB + b];
  float sqw = accum[2 * NB + b];
  float sm2 = accum[3 * NB + b];
  float shm = accum[4 * NB + b];
  float mean = sm1 / sw;
  float sem = sm2 + sqw * mean * mean - 2.0f * shm * mean;
  sem = sqrtf(sem / (float)(NSAMP * (NSAMP - 1)));
  out[b] = mean;
  out[NB + b] = sem;
}

// ------------------------------- launcher ----------------------------------
extern "C" void kernel_launch(void* const* d_in, const int* in_sizes, int n_in,
                              void* d_out, int out_size, void* d_ws, size_t ws_size,
                              hipStream_t stream) {
  (void)in_sizes; (void)n_in; (void)out_size; (void)ws_size;
  const float* inp  = (const float*)d_in[0];
  const float* pert = (const float*)d_in[1];
  const float* W_ih = (const float*)d_in[2];
  const float* W_hh = (const float*)d_in[3];
  const float* bias = (const float*)d_in[4];
  const float* w_mu = (const float*)d_in[5];
  const float* b_mu = (const float*)d_in[6];
  const float* w_ls = (const float*)d_in[7];
  const float* b_ls = (const float*)d_in[8];

  char* ws = (char*)d_ws;
  float* ret = (float*)ws;        ws += (size_t)NRET * NB * sizeof(float);
  float* hh  = (float*)ws;        ws += (size_t)NB * HH * sizeof(float);
  float* cc  = (float*)ws;        ws += (size_t)NB * HH * sizeof(float);
  uint32_t* keys = (uint32_t*)ws; ws += (size_t)NSAMP * NSTEP * 2 * sizeof(uint32_t);
  float* accum = (float*)ws;      // 5 * NB floats

  hipMemsetAsync(accum, 0, (size_t)5 * NB * sizeof(float), stream);
  returns_kernel<<<(NRET * NB + 255) / 256, 256, 0, stream>>>(inp, pert, ret);
  keys_kernel<<<(NSAMP * NSTEP + 255) / 256, 256, 0, stream>>>(keys);
  hist_kernel<<<NB / 32, 256, 0, stream>>>(ret, W_ih, W_hh, bias, hh, cc);
  mc_kernel<<<NSAMP * (NB / 64), 256, 0, stream>>>(ret, hh, cc, W_ih, W_hh, bias,
                                                   w_mu, b_mu, w_ls, b_ls, keys, accum);
  final_kernel<<<NB / 256, 256, 0, stream>>>(accum, (float*)d_out);
}

// Round 3
// 26299.103 us; speedup vs baseline: 1.3464x; 1.1845x over previous
//
#include <hip/hip_runtime.h>
#include <stdint.h>
#include <math.h>

// ---------------------------------------------------------------------------
// Round 3: split-bf16 MFMA (32x32x16) LSTM. a*b = ah*bh + al*bh + ah*bl
// (drop al*bl, err ~2^-18 rel). W_hh pre-split into B-fragment layout in
// global (L2-resident). h kept in LDS in A-fragment layout (hi/lo bf16,
// double-buffered). c and gate accumulators live in C-layout registers.
// mu/ls = one extra zero-padded MFMA matmul on wave 0 (hi-only, err ~1e-4).
// Fragment maps (m74/m101-verified C/D; A/B per gfx950 2xK convention):
//   A[m=lane&31][k=8*(lane>>5)+j], B[k=8*(lane>>5)+j][n=lane&31],
//   C row=(reg&3)+8*(reg>>2)+4*(lane>>5), col=lane&31.
// ---------------------------------------------------------------------------

#define HH     128
#define NG     512
#define NB     8192
#define NSAMP  100
#define NSTEP  20
#define TCAP   18
#define NHIST  126
#define NRET   127

using bfrag = __attribute__((ext_vector_type(8))) short;   // 8 bf16 = 4 VGPRs
using facc  = __attribute__((ext_vector_type(16))) float;  // 16 f32 acc

// ----------------------------- threefry2x32 --------------------------------
__device__ __forceinline__ void tf2x32(uint32_t k0, uint32_t k1,
                                       uint32_t x0, uint32_t x1,
                                       uint32_t &y0, uint32_t &y1) {
  uint32_t ks2 = k0 ^ k1 ^ 0x1BD11BDAu;
  x0 += k0; x1 += k1;
#define RR(r) { x0 += x1; x1 = (x1 << (r)) | (x1 >> (32 - (r))); x1 ^= x0; }
  RR(13) RR(15) RR(26) RR(6)   x0 += k1;  x1 += ks2 + 1u;
  RR(17) RR(29) RR(16) RR(24)  x0 += ks2; x1 += k0  + 2u;
  RR(13) RR(15) RR(26) RR(6)   x0 += k0;  x1 += k1  + 3u;
  RR(17) RR(29) RR(16) RR(24)  x0 += k1;  x1 += ks2 + 4u;
  RR(13) RR(15) RR(26) RR(6)   x0 += ks2; x1 += k0  + 5u;
#undef RR
  y0 = x0; y1 = x1;
}

__device__ __forceinline__ float erfinv32(float x) {
  float w = -log1pf(-x * x);
  float p;
  if (w < 5.0f) {
    w = w - 2.5f;
    p = 2.81022636e-08f;
    p = fmaf(p, w, 3.43273939e-07f);
    p = fmaf(p, w, -3.5233877e-06f);
    p = fmaf(p, w, -4.39150654e-06f);
    p = fmaf(p, w, 0.00021858087f);
    p = fmaf(p, w, -0.00125372503f);
    p = fmaf(p, w, -0.00417768164f);
    p = fmaf(p, w, 0.246640727f);
    p = fmaf(p, w, 1.50140941f);
  } else {
    w = sqrtf(w) - 3.0f;
    p = -0.000200214257f;
    p = fmaf(p, w, 0.000100950558f);
    p = fmaf(p, w, 0.00134934322f);
    p = fmaf(p, w, -0.00367342844f);
    p = fmaf(p, w, 0.00573950773f);
    p = fmaf(p, w, -0.0076224613f);
    p = fmaf(p, w, 0.00943887047f);
    p = fmaf(p, w, 1.00167406f);
    p = fmaf(p, w, 2.83297682f);
  }
  return p * x;
}

__device__ __forceinline__ float normal32(uint32_t k0, uint32_t k1, uint32_t idx) {
  uint32_t y0, y1;
  tf2x32(k0, k1, 0u, idx, y0, y1);
  uint32_t bits = y0 ^ y1;
  float f = __uint_as_float((bits >> 9) | 0x3f800000u) - 1.0f;
  const float lo = __uint_as_float(0xBF7FFFFFu);
  float u = fmaxf(lo, f * 2.0f + lo);
  return 1.41421356f * erfinv32(u);
}

__device__ __forceinline__ float fast_sigmoid(float x) {
  return __builtin_amdgcn_rcpf(1.0f + __expf(-x));
}
__device__ __forceinline__ float fast_tanh(float x) {
  return 1.0f - 2.0f * __builtin_amdgcn_rcpf(1.0f + __expf(2.0f * x));
}

// bf16 split helpers (RNE)
__device__ __forceinline__ unsigned short f2bf(float x) {
  uint32_t u = __float_as_uint(x);
  uint32_t r = u + 0x7fffu + ((u >> 16) & 1u);
  return (unsigned short)(r >> 16);
}
__device__ __forceinline__ float bf2f(unsigned short h) {
  return __uint_as_float(((uint32_t)h) << 16);
}

// ------------------------------- small kernels -----------------------------
__global__ void returns_kernel(const float* __restrict__ inp,
                               const float* __restrict__ pert,
                               float* __restrict__ ret) {
  int i = blockIdx.x * blockDim.x + threadIdx.x;
  if (i >= NRET * NB) return;
  int s = i / NB, b = i - s * NB;
  float p0 = inp[s * NB + b] * (1.0f + pert[s * NB + b]);
  float p1 = inp[(s + 1) * NB + b] * (1.0f + pert[(s + 1) * NB + b]);
  ret[i] = p1 - p0;
}

__global__ void keys_kernel(uint32_t* __restrict__ keys) {
  int id = blockIdx.x * blockDim.x + threadIdx.x;
  if (id >= NSAMP * NSTEP) return;
  int s = id / NSTEP, t = id - s * NSTEP;
  uint32_t sk0, sk1, k0, k1;
  tf2x32(0u, 42u, 0u, (uint32_t)s, sk0, sk1);
  tf2x32(sk0, sk1, 0u, (uint32_t)t, k0, k1);
  keys[2 * id] = k0; keys[2 * id + 1] = k1;
}

// Pre-split W_hh into B-fragment layout: Bhi/Blo[((gct*8+kb)*64+lane)*8+j]
//   k = kb*16 + 8*(lane>>5) + j, g = 32*gct + (lane&31).
// Bmu[(kb*64+lane)*8+j]: col0 = w_mu, col1 = w_ls, else 0 (hi only).
__global__ void pack_kernel(const float* __restrict__ W_hh,
                            const float* __restrict__ w_mu,
                            const float* __restrict__ w_ls,
                            unsigned short* __restrict__ Bhi,
                            unsigned short* __restrict__ Blo,
                            unsigned short* __restrict__ Bmu) {
  int idx = blockIdx.x * blockDim.x + threadIdx.x;
  if (idx < 65536) {
    int j = idx & 7, lane = (idx >> 3) & 63, kb = (idx >> 9) & 7, gct = idx >> 12;
    int k = kb * 16 + ((lane >> 5) << 3) + j;
    int g = (gct << 5) + (lane & 31);
    float w = W_hh[k * NG + g];
    unsigned short hi = f2bf(w);
    unsigned short lo = f2bf(w - bf2f(hi));
    Bhi[idx] = hi; Blo[idx] = lo;
  } else if (idx < 65536 + 4096) {
    int i2 = idx - 65536;
    int j = i2 & 7, lane = (i2 >> 3) & 63, kb = (i2 >> 9) & 7;
    int k = kb * 16 + ((lane >> 5) << 3) + j;
    int col = lane & 31;
    float v = (col == 0) ? w_mu[k] : (col == 1 ? w_ls[k] : 0.0f);
    Bmu[i2] = f2bf(v);
  }
}

// ------------------------------ main LSTM kernel ---------------------------
// 64 rows/block, 256 threads = 4 waves; wave cg owns hidden cols 32cg..+31
// across gates i,f,g,o => 8 MFMA tiles (2 row-tiles x 4 gates).
template<bool STOCH>
__launch_bounds__(256, 2)
__global__ void lstm_kernel(const float* __restrict__ ret,
                            const float* __restrict__ W_ih,
                            const float* __restrict__ bias,
                            const unsigned short* __restrict__ Bhi,
                            const unsigned short* __restrict__ Blo,
                            const unsigned short* __restrict__ Bmu,
                            const float* __restrict__ hin,
                            const float* __restrict__ cin,
                            float* __restrict__ hout,
                            float* __restrict__ cout,
                            const float* __restrict__ b_mu,
                            const float* __restrict__ b_ls,
                            const uint32_t* __restrict__ keys,
                            float* __restrict__ accum) {
  __shared__ unsigned short hfh[2][2][4096];  // [buf][rt][kb*512 + lane*8 + j]
  __shared__ unsigned short hfl[2][2][4096];
  __shared__ float x_s[64];
  __shared__ float mu_s[64];
  __shared__ float ls_s[64];

  const int tid  = threadIdx.x;
  const int lane = tid & 63;
  const int cg   = tid >> 6;          // wave id = hidden-col group
  const int hs   = lane >> 5;         // half-wave (k/row-half selector)
  const int col  = (cg << 5) + (lane & 31);   // hidden col owned in epilogue

  int s, b0;
  if (STOCH) { s = blockIdx.x >> 7; b0 = (blockIdx.x & 127) << 6; }
  else       { s = 0;               b0 = blockIdx.x << 6; }

  // per-lane W_ih / bias for the 4 gates at this hidden col (fp32 exact)
  float wih_r[4], bb_r[4];
#pragma unroll
  for (int gi = 0; gi < 4; ++gi) {
    wih_r[gi] = W_ih[(gi << 7) + col];
    bb_r[gi]  = bias[(gi << 7) + col];
  }
  const float bmu = b_mu[0], bls = b_ls[0];

  // epilogue frag-write offset for this lane's column (row32*8 added later)
  const int coff = (col >> 4) * 512 + ((col >> 3) & 1) * 256 + (col & 7);

  // ---- init h frags (buf 0) + c registers
  float c_reg[2][16];
#pragma unroll
  for (int rt = 0; rt < 2; ++rt) {
#pragma unroll
    for (int reg = 0; reg < 16; ++reg) {
      int row32 = (reg & 3) + ((reg >> 2) << 3) + (hs << 2);
      float hv = 0.0f, cv = 0.0f;
      if (STOCH) {
        int grow = b0 + (rt << 5) + row32;
        hv = hin[grow * HH + col];
        cv = cin[grow * HH + col];
      }
      c_reg[rt][reg] = cv;
      unsigned short hi = f2bf(hv);
      unsigned short lo = f2bf(hv - bf2f(hi));
      hfh[0][rt][coff + row32 * 8] = hi;
      hfl[0][rt][coff + row32 * 8] = lo;
    }
  }
  if (STOCH && tid < 64) x_s[tid] = ret[126 * NB + b0 + tid];
  float logw = 0.0f, outv = 0.0f;
  __syncthreads();

  const int nsteps = STOCH ? NSTEP : NHIST;
  int buf = 0;
  for (int t = 0; t < nsteps; ++t) {
    const int nbuf = buf ^ 1;

    // ---- C init: x*W_ih + b (fp32 exact)
    facc acc[8];
#pragma unroll
    for (int rt = 0; rt < 2; ++rt) {
#pragma unroll
      for (int reg = 0; reg < 16; ++reg) {
        int row32 = (reg & 3) + ((reg >> 2) << 3) + (hs << 2);
        float xv;
        if (STOCH) xv = x_s[(rt << 5) + row32];
        else       xv = ret[t * NB + b0 + (rt << 5) + row32];
#pragma unroll
        for (int gi = 0; gi < 4; ++gi)
          acc[gi * 2 + rt][reg] = fmaf(xv, wih_r[gi], bb_r[gi]);
      }
    }

    // ---- gate matmul: 3-term split-bf16, 192 MFMAs
#pragma unroll
    for (int kb = 0; kb < 8; ++kb) {
      bfrag ah[2], al[2];
#pragma unroll
      for (int rt = 0; rt < 2; ++rt) {
        ah[rt] = *(const bfrag*)&hfh[buf][rt][kb * 512 + lane * 8];
        al[rt] = *(const bfrag*)&hfl[buf][rt][kb * 512 + lane * 8];
      }
#pragma unroll
      for (int gi = 0; gi < 4; ++gi) {
        const int gct = (gi << 2) + cg;
        const bfrag bh = *(const bfrag*)&Bhi[((gct << 3) + kb) * 512 + lane * 8];
        const bfrag bl = *(const bfrag*)&Blo[((gct << 3) + kb) * 512 + lane * 8];
        acc[gi*2+0] = __builtin_amdgcn_mfma_f32_32x32x16_bf16(ah[0], bh, acc[gi*2+0], 0, 0, 0);
        acc[gi*2+1] = __builtin_amdgcn_mfma_f32_32x32x16_bf16(ah[1], bh, acc[gi*2+1], 0, 0, 0);
        acc[gi*2+0] = __builtin_amdgcn_mfma_f32_32x32x16_bf16(al[0], bh, acc[gi*2+0], 0, 0, 0);
        acc[gi*2+1] = __builtin_amdgcn_mfma_f32_32x32x16_bf16(al[1], bh, acc[gi*2+1], 0, 0, 0);
        acc[gi*2+0] = __builtin_amdgcn_mfma_f32_32x32x16_bf16(ah[0], bl, acc[gi*2+0], 0, 0, 0);
        acc[gi*2+1] = __builtin_amdgcn_mfma_f32_32x32x16_bf16(ah[1], bl, acc[gi*2+1], 0, 0, 0);
      }
    }

    // ---- epilogue: cell update in C-layout regs, write h frags to nbuf
#pragma unroll
    for (int rt = 0; rt < 2; ++rt) {
#pragma unroll
      for (int reg = 0; reg < 16; ++reg) {
        int row32 = (reg & 3) + ((reg >> 2) << 3) + (hs << 2);
        float ig = fast_sigmoid(acc[0 * 2 + rt][reg]);
        float fg = fast_sigmoid(acc[1 * 2 + rt][reg]);
        float gg = fast_tanh  (acc[2 * 2 + rt][reg]);
        float og = fast_sigmoid(acc[3 * 2 + rt][reg]);
        float c  = fmaf(fg, c_reg[rt][reg], ig * gg);
        c_reg[rt][reg] = c;
        float h  = og * fast_tanh(c);
        unsigned short hi = f2bf(h);
        unsigned short lo = f2bf(h - bf2f(hi));
        hfh[nbuf][rt][coff + row32 * 8] = hi;
        hfl[nbuf][rt][coff + row32 * 8] = lo;
        if (!STOCH && t == NHIST - 1)
          hout[(b0 + (rt << 5) + row32) * HH + col] = h;
      }
    }
    __syncthreads();   // B1: new h frags visible (also guards old-buf reuse)

    if (STOCH) {
      if (tid < 64) {   // wave 0: mu/ls MFMA + RNG + x update
        facc am[2];
#pragma unroll
        for (int rt = 0; rt < 2; ++rt)
#pragma unroll
          for (int e = 0; e < 16; ++e) am[rt][e] = 0.0f;
#pragma unroll
        for (int kb = 0; kb < 8; ++kb) {
          const bfrag bm = *(const bfrag*)&Bmu[kb * 512 + lane * 8];
#pragma unroll
          for (int rt = 0; rt < 2; ++rt) {
            const bfrag ahh = *(const bfrag*)&hfh[nbuf][rt][kb * 512 + lane * 8];
            am[rt] = __builtin_amdgcn_mfma_f32_32x32x16_bf16(ahh, bm, am[rt], 0, 0, 0);
          }
        }
        if ((lane & 31) < 2) {
          float* dst = ((lane & 31) == 0) ? mu_s : ls_s;
#pragma unroll
          for (int rt = 0; rt < 2; ++rt)
#pragma unroll
            for (int reg = 0; reg < 16; ++reg)
              dst[(rt << 5) + (reg & 3) + ((reg >> 2) << 3) + (hs << 2)] = am[rt][reg];
        }
        // same-wave LDS RAW: compiler inserts lgkmcnt wait
        float mu  = mu_s[lane] + bmu;
        float lsc = fminf(fmaxf(ls_s[lane] + bls, -5.0f), 2.0f);
        float sg  = __expf(lsc);
        uint32_t k0 = keys[2 * (s * NSTEP + t)];
        uint32_t k1 = keys[2 * (s * NSTEP + t) + 1];
        float z  = normal32(k0, k1, (uint32_t)(b0 + lane));
        float xn = fmaf(sg, z + 0.5f, mu);
        logw -= fmaf(0.5f, z, 0.125f);
        if (t == TCAP) outv = xn;
        x_s[lane] = xn;
      }
      __syncthreads();  // B2: x_s ready
    }
    buf = nbuf;
  }

  if (STOCH) {
    if (tid < 64) {
      float w  = __expf(logw);
      float ow = outv * w;
      int b = b0 + tid;
      atomicAdd(&accum[0 * NB + b], w);
      atomicAdd(&accum[1 * NB + b], ow);
      atomicAdd(&accum[2 * NB + b], w * w);
      atomicAdd(&accum[3 * NB + b], ow * ow);
      atomicAdd(&accum[4 * NB + b], outv * w * w);
    }
  } else {
#pragma unroll
    for (int rt = 0; rt < 2; ++rt)
#pragma unroll
      for (int reg = 0; reg < 16; ++reg) {
        int row32 = (reg & 3) + ((reg >> 2) << 3) + (hs << 2);
        cout[(b0 + (rt << 5) + row32) * HH + col] = c_reg[rt][reg];
      }
  }
}

// ------------------------------- final kernel ------------------------------
__global__ void final_kernel(const float* __restrict__ accum,
                             float* __restrict__ out) {
  int b = blockIdx.x * blockDim.x + threadIdx.x;
  if (b >= NB) return;
  float sw  = accum[0 * NB + b];
  float sm1 = accum[1 * NB + b];
  float sqw = accum[2 * NB + b];
  float sm2 = accum[3 * NB + b];
  float shm = accum[4 * NB + b];
  float mean = sm1 / sw;
  float sem = sm2 + sqw * mean * mean - 2.0f * shm * mean;
  sem = sqrtf(sem / (float)(NSAMP * (NSAMP - 1)));
  out[b] = mean;
  out[NB + b] = sem;
}

// ------------------------------- launcher ----------------------------------
extern "C" void kernel_launch(void* const* d_in, const int* in_sizes, int n_in,
                              void* d_out, int out_size, void* d_ws, size_t ws_size,
                              hipStream_t stream) {
  (void)in_sizes; (void)n_in; (void)out_size; (void)ws_size;
  const float* inp  = (const float*)d_in[0];
  const float* pert = (const float*)d_in[1];
  const float* W_ih = (const float*)d_in[2];
  const float* W_hh = (const float*)d_in[3];
  const float* bias = (const float*)d_in[4];
  const float* w_mu = (const float*)d_in[5];
  const float* b_mu = (const float*)d_in[6];
  const float* w_ls = (const float*)d_in[7];
  const float* b_ls = (const float*)d_in[8];

  char* ws = (char*)d_ws;
  float* ret = (float*)ws;        ws += (size_t)NRET * NB * sizeof(float);
  float* hh  = (float*)ws;        ws += (size_t)NB * HH * sizeof(float);
  float* cc  = (float*)ws;        ws += (size_t)NB * HH * sizeof(float);
  uint32_t* keys = (uint32_t*)ws; ws += (size_t)NSAMP * NSTEP * 2 * sizeof(uint32_t);
  float* accum = (float*)ws;      ws += (size_t)5 * NB * sizeof(float);
  unsigned short* Bhi = (unsigned short*)ws; ws += 65536 * sizeof(unsigned short);
  unsigned short* Blo = (unsigned short*)ws; ws += 65536 * sizeof(unsigned short);
  unsigned short* Bmu = (unsigned short*)ws; ws += 4096 * sizeof(unsigned short);

  hipMemsetAsync(accum, 0, (size_t)5 * NB * sizeof(float), stream);
  returns_kernel<<<(NRET * NB + 255) / 256, 256, 0, stream>>>(inp, pert, ret);
  keys_kernel<<<(NSAMP * NSTEP + 255) / 256, 256, 0, stream>>>(keys);
  pack_kernel<<<(65536 + 4096) / 256, 256, 0, stream>>>(W_hh, w_mu, w_ls, Bhi, Blo, Bmu);
  lstm_kernel<false><<<NB / 64, 256, 0, stream>>>(ret, W_ih, bias, Bhi, Blo, Bmu,
      nullptr, nullptr, hh, cc, b_mu, b_ls, keys, nullptr);
  lstm_kernel<true><<<NSAMP * (NB / 64), 256, 0, stream>>>(ret, W_ih, bias, Bhi, Blo, Bmu,
      hh, cc, nullptr, nullptr, b_mu, b_ls, keys, accum);
  final_kernel<<<NB / 256, 256, 0, stream>>>(accum, (float*)d_out);
}

// Round 5
// 18758.772 us; speedup vs baseline: 1.8875x; 1.4020x over previous
//
#include <hip/hip_runtime.h>
#include <stdint.h>
#include <math.h>

// ---------------------------------------------------------------------------
// Round 5: R3 algorithm (split-bf16 MFMA 32x32x16 LSTM, double-buffered h in
// LDS A-frag layout, B pre-split in global), with the spill cause removed:
// the kb loop is NOT unrolled (#pragma unroll 1) and each kb's 8 B-fragment
// loads are grouped at the top of the body. R3's full kb x gi unroll let the
// scheduler hoist up to 64 global_load_dwordx4 (256 VGPRs of B) past the
// 128-VGPR cap of __launch_bounds__(256,2) -> ~50 spilled regs -> 14.5 GB
// scratch writes + L2 eviction of the B table (56 GB HBM fetch).
// Steady-state VGPR need now ~110 (c 32 + A 16 + one kb's B 32 + misc),
// acc stays in 128 AGPRs. R4's unbounded variant crashed; (256,2) is the
// known-stable occupancy config (2 blocks/CU).
// ---------------------------------------------------------------------------

#define HH     128
#define NG     512
#define NB     8192
#define NSAMP  100
#define NSTEP  20
#define TCAP   18
#define NHIST  126
#define NRET   127

using bfrag = __attribute__((ext_vector_type(8))) short;   // 8 bf16 = 4 VGPRs
using facc  = __attribute__((ext_vector_type(16))) float;  // 16 f32 acc

// ----------------------------- threefry2x32 --------------------------------
__device__ __forceinline__ void tf2x32(uint32_t k0, uint32_t k1,
                                       uint32_t x0, uint32_t x1,
                                       uint32_t &y0, uint32_t &y1) {
  uint32_t ks2 = k0 ^ k1 ^ 0x1BD11BDAu;
  x0 += k0; x1 += k1;
#define RR(r) { x0 += x1; x1 = (x1 << (r)) | (x1 >> (32 - (r))); x1 ^= x0; }
  RR(13) RR(15) RR(26) RR(6)   x0 += k1;  x1 += ks2 + 1u;
  RR(17) RR(29) RR(16) RR(24)  x0 += ks2; x1 += k0  + 2u;
  RR(13) RR(15) RR(26) RR(6)   x0 += k0;  x1 += k1  + 3u;
  RR(17) RR(29) RR(16) RR(24)  x0 += k1;  x1 += ks2 + 4u;
  RR(13) RR(15) RR(26) RR(6)   x0 += ks2; x1 += k0  + 5u;
#undef RR
  y0 = x0; y1 = x1;
}

__device__ __forceinline__ float erfinv32(float x) {
  float w = -log1pf(-x * x);
  float p;
  if (w < 5.0f) {
    w = w - 2.5f;
    p = 2.81022636e-08f;
    p = fmaf(p, w, 3.43273939e-07f);
    p = fmaf(p, w, -3.5233877e-06f);
    p = fmaf(p, w, -4.39150654e-06f);
    p = fmaf(p, w, 0.00021858087f);
    p = fmaf(p, w, -0.00125372503f);
    p = fmaf(p, w, -0.00417768164f);
    p = fmaf(p, w, 0.246640727f);
    p = fmaf(p, w, 1.50140941f);
  } else {
    w = sqrtf(w) - 3.0f;
    p = -0.000200214257f;
    p = fmaf(p, w, 0.000100950558f);
    p = fmaf(p, w, 0.00134934322f);
    p = fmaf(p, w, -0.00367342844f);
    p = fmaf(p, w, 0.00573950773f);
    p = fmaf(p, w, -0.0076224613f);
    p = fmaf(p, w, 0.00943887047f);
    p = fmaf(p, w, 1.00167406f);
    p = fmaf(p, w, 2.83297682f);
  }
  return p * x;
}

__device__ __forceinline__ float normal32(uint32_t k0, uint32_t k1, uint32_t idx) {
  uint32_t y0, y1;
  tf2x32(k0, k1, 0u, idx, y0, y1);
  uint32_t bits = y0 ^ y1;
  float f = __uint_as_float((bits >> 9) | 0x3f800000u) - 1.0f;
  const float lo = __uint_as_float(0xBF7FFFFFu);
  float u = fmaxf(lo, f * 2.0f + lo);
  return 1.41421356f * erfinv32(u);
}

__device__ __forceinline__ float fast_sigmoid(float x) {
  return __builtin_amdgcn_rcpf(1.0f + __expf(-x));
}
__device__ __forceinline__ float fast_tanh(float x) {
  return 1.0f - 2.0f * __builtin_amdgcn_rcpf(1.0f + __expf(2.0f * x));
}

// bf16 split helpers (RNE)
__device__ __forceinline__ unsigned short f2bf(float x) {
  uint32_t u = __float_as_uint(x);
  uint32_t r = u + 0x7fffu + ((u >> 16) & 1u);
  return (unsigned short)(r >> 16);
}
__device__ __forceinline__ float bf2f(unsigned short h) {
  return __uint_as_float(((uint32_t)h) << 16);
}

// ------------------------------- small kernels -----------------------------
__global__ void returns_kernel(const float* __restrict__ inp,
                               const float* __restrict__ pert,
                               float* __restrict__ ret) {
  int i = blockIdx.x * blockDim.x + threadIdx.x;
  if (i >= NRET * NB) return;
  int s = i / NB, b = i - s * NB;
  float p0 = inp[s * NB + b] * (1.0f + pert[s * NB + b]);
  float p1 = inp[(s + 1) * NB + b] * (1.0f + pert[(s + 1) * NB + b]);
  ret[i] = p1 - p0;
}

__global__ void keys_kernel(uint32_t* __restrict__ keys) {
  int id = blockIdx.x * blockDim.x + threadIdx.x;
  if (id >= NSAMP * NSTEP) return;
  int s = id / NSTEP, t = id - s * NSTEP;
  uint32_t sk0, sk1, k0, k1;
  tf2x32(0u, 42u, 0u, (uint32_t)s, sk0, sk1);
  tf2x32(sk0, sk1, 0u, (uint32_t)t, k0, k1);
  keys[2 * id] = k0; keys[2 * id + 1] = k1;
}

// Pre-split W_hh into B-fragment layout: Bhi/Blo[((gct*8+kb)*64+lane)*8+j]
//   k = kb*16 + 8*(lane>>5) + j, g = 32*gct + (lane&31).
// Bmu[(kb*64+lane)*8+j]: col0 = w_mu, col1 = w_ls, else 0 (hi only).
__global__ void pack_kernel(const float* __restrict__ W_hh,
                            const float* __restrict__ w_mu,
                            const float* __restrict__ w_ls,
                            unsigned short* __restrict__ Bhi,
                            unsigned short* __restrict__ Blo,
                            unsigned short* __restrict__ Bmu) {
  int idx = blockIdx.x * blockDim.x + threadIdx.x;
  if (idx < 65536) {
    int j = idx & 7, lane = (idx >> 3) & 63, kb = (idx >> 9) & 7, gct = idx >> 12;
    int k = kb * 16 + ((lane >> 5) << 3) + j;
    int g = (gct << 5) + (lane & 31);
    float w = W_hh[k * NG + g];
    unsigned short hi = f2bf(w);
    unsigned short lo = f2bf(w - bf2f(hi));
    Bhi[idx] = hi; Blo[idx] = lo;
  } else if (idx < 65536 + 4096) {
    int i2 = idx - 65536;
    int j = i2 & 7, lane = (i2 >> 3) & 63, kb = (i2 >> 9) & 7;
    int k = kb * 16 + ((lane >> 5) << 3) + j;
    int col = lane & 31;
    float v = (col == 0) ? w_mu[k] : (col == 1 ? w_ls[k] : 0.0f);
    Bmu[i2] = f2bf(v);
  }
}

// ------------------------------ main LSTM kernel ---------------------------
// 64 rows/block, 256 threads = 4 waves; wave cg owns hidden cols 32cg..+31
// across gates i,f,g,o => 8 MFMA tiles (2 row-tiles x 4 gates).
template<bool STOCH>
__launch_bounds__(256, 2)   // known-stable; spills avoided via unroll-1 kb loop
__global__ void lstm_kernel(const float* __restrict__ ret,
                            const float* __restrict__ W_ih,
                            const float* __restrict__ bias,
                            const unsigned short* __restrict__ Bhi,
                            const unsigned short* __restrict__ Blo,
                            const unsigned short* __restrict__ Bmu,
                            const float* __restrict__ hin,
                            const float* __restrict__ cin,
                            float* __restrict__ hout,
                            float* __restrict__ cout,
                            const float* __restrict__ b_mu,
                            const float* __restrict__ b_ls,
                            const uint32_t* __restrict__ keys,
                            float* __restrict__ accum) {
  __shared__ unsigned short hfh[2][2][4096];  // [buf][rt][kb*512 + lane*8 + j]
  __shared__ unsigned short hfl[2][2][4096];
  __shared__ float x_s[64];
  __shared__ float mu_s[64];
  __shared__ float ls_s[64];

  const int tid  = threadIdx.x;
  const int lane = tid & 63;
  const int cg   = tid >> 6;          // wave id = hidden-col group
  const int hs   = lane >> 5;         // half-wave (k/row-half selector)
  const int col  = (cg << 5) + (lane & 31);   // hidden col owned in epilogue

  int s, b0;
  if (STOCH) { s = blockIdx.x >> 7; b0 = (blockIdx.x & 127) << 6; }
  else       { s = 0;               b0 = blockIdx.x << 6; }

  // per-lane W_ih / bias for the 4 gates at this hidden col (fp32 exact)
  float wih_r[4], bb_r[4];
#pragma unroll
  for (int gi = 0; gi < 4; ++gi) {
    wih_r[gi] = W_ih[(gi << 7) + col];
    bb_r[gi]  = bias[(gi << 7) + col];
  }
  const float bmu = b_mu[0], bls = b_ls[0];

  // epilogue frag-write offset for this lane's column (row32*8 added later)
  const int coff = (col >> 4) * 512 + ((col >> 3) & 1) * 256 + (col & 7);

  // ---- init h frags (buf 0) + c registers
  float c_reg[2][16];
#pragma unroll
  for (int rt = 0; rt < 2; ++rt) {
#pragma unroll
    for (int reg = 0; reg < 16; ++reg) {
      int row32 = (reg & 3) + ((reg >> 2) << 3) + (hs << 2);
      float hv = 0.0f, cv = 0.0f;
      if (STOCH) {
        int grow = b0 + (rt << 5) + row32;
        hv = hin[grow * HH + col];
        cv = cin[grow * HH + col];
      }
      c_reg[rt][reg] = cv;
      unsigned short hi = f2bf(hv);
      unsigned short lo = f2bf(hv - bf2f(hi));
      hfh[0][rt][coff + row32 * 8] = hi;
      hfl[0][rt][coff + row32 * 8] = lo;
    }
  }
  if (STOCH && tid < 64) x_s[tid] = ret[126 * NB + b0 + tid];
  float logw = 0.0f, outv = 0.0f;
  __syncthreads();

  const int nsteps = STOCH ? NSTEP : NHIST;
  int buf = 0;
  for (int t = 0; t < nsteps; ++t) {
    const int nbuf = buf ^ 1;

    // ---- C init: x*W_ih + b (fp32 exact)
    facc acc[8];
#pragma unroll
    for (int rt = 0; rt < 2; ++rt) {
#pragma unroll
      for (int reg = 0; reg < 16; ++reg) {
        int row32 = (reg & 3) + ((reg >> 2) << 3) + (hs << 2);
        float xv;
        if (STOCH) xv = x_s[(rt << 5) + row32];
        else       xv = ret[t * NB + b0 + (rt << 5) + row32];
#pragma unroll
        for (int gi = 0; gi < 4; ++gi)
          acc[gi * 2 + rt][reg] = fmaf(xv, wih_r[gi], bb_r[gi]);
      }
    }

    // ---- gate matmul: 3-term split-bf16, 192 MFMAs/wave.
    // kb NOT unrolled: keeps only one kb's B frags (32 VGPRs) live.
#pragma unroll 1
    for (int kb = 0; kb < 8; ++kb) {
      // batched loads for this kb: 4 LDS A-frags + 8 global B-frags
      bfrag ah0 = *(const bfrag*)&hfh[buf][0][kb * 512 + lane * 8];
      bfrag ah1 = *(const bfrag*)&hfh[buf][1][kb * 512 + lane * 8];
      bfrag al0 = *(const bfrag*)&hfl[buf][0][kb * 512 + lane * 8];
      bfrag al1 = *(const bfrag*)&hfl[buf][1][kb * 512 + lane * 8];
      bfrag bh[4], bl[4];
#pragma unroll
      for (int gi = 0; gi < 4; ++gi) {
        const int off = ((((gi << 2) + cg) << 3) + kb) * 512 + lane * 8;
        bh[gi] = *(const bfrag*)&Bhi[off];
        bl[gi] = *(const bfrag*)&Blo[off];
      }
#pragma unroll
      for (int gi = 0; gi < 4; ++gi) {
        acc[gi*2+0] = __builtin_amdgcn_mfma_f32_32x32x16_bf16(ah0, bh[gi], acc[gi*2+0], 0, 0, 0);
        acc[gi*2+1] = __builtin_amdgcn_mfma_f32_32x32x16_bf16(ah1, bh[gi], acc[gi*2+1], 0, 0, 0);
        acc[gi*2+0] = __builtin_amdgcn_mfma_f32_32x32x16_bf16(al0, bh[gi], acc[gi*2+0], 0, 0, 0);
        acc[gi*2+1] = __builtin_amdgcn_mfma_f32_32x32x16_bf16(al1, bh[gi], acc[gi*2+1], 0, 0, 0);
        acc[gi*2+0] = __builtin_amdgcn_mfma_f32_32x32x16_bf16(ah0, bl[gi], acc[gi*2+0], 0, 0, 0);
        acc[gi*2+1] = __builtin_amdgcn_mfma_f32_32x32x16_bf16(ah1, bl[gi], acc[gi*2+1], 0, 0, 0);
      }
    }

    // ---- epilogue: cell update in C-layout regs, write h frags to nbuf
#pragma unroll
    for (int rt = 0; rt < 2; ++rt) {
#pragma unroll
      for (int reg = 0; reg < 16; ++reg) {
        int row32 = (reg & 3) + ((reg >> 2) << 3) + (hs << 2);
        float ig = fast_sigmoid(acc[0 * 2 + rt][reg]);
        float fg = fast_sigmoid(acc[1 * 2 + rt][reg]);
        float gg = fast_tanh  (acc[2 * 2 + rt][reg]);
        float og = fast_sigmoid(acc[3 * 2 + rt][reg]);
        float c  = fmaf(fg, c_reg[rt][reg], ig * gg);
        c_reg[rt][reg] = c;
        float h  = og * fast_tanh(c);
        unsigned short hi = f2bf(h);
        unsigned short lo = f2bf(h - bf2f(hi));
        hfh[nbuf][rt][coff + row32 * 8] = hi;
        hfl[nbuf][rt][coff + row32 * 8] = lo;
        if (!STOCH && t == NHIST - 1)
          hout[(b0 + (rt << 5) + row32) * HH + col] = h;
      }
    }
    __syncthreads();   // B1: new h frags visible (also guards old-buf reuse)

    if (STOCH) {
      if (tid < 64) {   // wave 0: mu/ls MFMA + RNG + x update
        facc am[2];
#pragma unroll
        for (int rt = 0; rt < 2; ++rt)
#pragma unroll
          for (int e = 0; e < 16; ++e) am[rt][e] = 0.0f;
#pragma unroll 1
        for (int kb = 0; kb < 8; ++kb) {
          const bfrag bm = *(const bfrag*)&Bmu[kb * 512 + lane * 8];
          const bfrag a0 = *(const bfrag*)&hfh[nbuf][0][kb * 512 + lane * 8];
          const bfrag a1 = *(const bfrag*)&hfh[nbuf][1][kb * 512 + lane * 8];
          am[0] = __builtin_amdgcn_mfma_f32_32x32x16_bf16(a0, bm, am[0], 0, 0, 0);
          am[1] = __builtin_amdgcn_mfma_f32_32x32x16_bf16(a1, bm, am[1], 0, 0, 0);
        }
        if ((lane & 31) < 2) {
          float* dst = ((lane & 31) == 0) ? mu_s : ls_s;
#pragma unroll
          for (int rt = 0; rt < 2; ++rt)
#pragma unroll
            for (int reg = 0; reg < 16; ++reg)
              dst[(rt << 5) + (reg & 3) + ((reg >> 2) << 3) + (hs << 2)] = am[rt][reg];
        }
        // same-wave LDS RAW: compiler inserts lgkmcnt wait
        float mu  = mu_s[lane] + bmu;
        float lsc = fminf(fmaxf(ls_s[lane] + bls, -5.0f), 2.0f);
        float sg  = __expf(lsc);
        uint32_t k0 = keys[2 * (s * NSTEP + t)];
        uint32_t k1 = keys[2 * (s * NSTEP + t) + 1];
        float z  = normal32(k0, k1, (uint32_t)(b0 + lane));
        float xn = fmaf(sg, z + 0.5f, mu);
        logw -= fmaf(0.5f, z, 0.125f);
        if (t == TCAP) outv = xn;
        x_s[lane] = xn;
      }
      __syncthreads();  // B2: x_s ready
    }
    buf = nbuf;
  }

  if (STOCH) {
    if (tid < 64) {
      float w  = __expf(logw);
      float ow = outv * w;
      int b = b0 + tid;
      atomicAdd(&accum[0 * NB + b], w);
      atomicAdd(&accum[1 * NB + b], ow);
      atomicAdd(&accum[2 * NB + b], w * w);
      atomicAdd(&accum[3 * NB + b], ow * ow);
      atomicAdd(&accum[4 * NB + b], outv * w * w);
    }
  } else {
#pragma unroll
    for (int rt = 0; rt < 2; ++rt)
#pragma unroll
      for (int reg = 0; reg < 16; ++reg) {
        int row32 = (reg & 3) + ((reg >> 2) << 3) + (hs << 2);
        cout[(b0 + (rt << 5) + row32) * HH + col] = c_reg[rt][reg];
      }
  }
}

// ------------------------------- final kernel ------------------------------
__global__ void final_kernel(const float* __restrict__ accum,
                             float* __restrict__ out) {
  int b = blockIdx.x * blockDim.x + threadIdx.x;
  if (b >= NB) return;
  float sw  = accum[0 * NB + b];
  float sm1 = accum[1 * NB + b];
  float sqw = accum[2 * NB + b];
  float sm2 = accum[3 * NB + b];
  float shm = accum[4 * NB + b];
  float mean = sm1 / sw;
  float sem = sm2 + sqw * mean * mean - 2.0f * shm * mean;
  sem = sqrtf(sem / (float)(NSAMP * (NSAMP - 1)));
  out[b] = mean;
  out[NB + b] = sem;
}

// ------------------------------- launcher ----------------------------------
extern "C" void kernel_launch(void* const* d_in, const int* in_sizes, int n_in,
                              void* d_out, int out_size, void* d_ws, size_t ws_size,
                              hipStream_t stream) {
  (void)in_sizes; (void)n_in; (void)out_size; (void)ws_size;
  const float* inp  = (const float*)d_in[0];
  const float* pert = (const float*)d_in[1];
  const float* W_ih = (const float*)d_in[2];
  const float* W_hh = (const float*)d_in[3];
  const float* bias = (const float*)d_in[4];
  const float* w_mu = (const float*)d_in[5];
  const float* b_mu = (const float*)d_in[6];
  const float* w_ls = (const float*)d_in[7];
  const float* b_ls = (const float*)d_in[8];

  char* ws = (char*)d_ws;
  float* ret = (float*)ws;        ws += (size_t)NRET * NB * sizeof(float);
  float* hh  = (float*)ws;        ws += (size_t)NB * HH * sizeof(float);
  float* cc  = (float*)ws;        ws += (size_t)NB * HH * sizeof(float);
  uint32_t* keys = (uint32_t*)ws; ws += (size_t)NSAMP * NSTEP * 2 * sizeof(uint32_t);
  float* accum = (float*)ws;      ws += (size_t)5 * NB * sizeof(float);
  unsigned short* Bhi = (unsigned short*)ws; ws += 65536 * sizeof(unsigned short);
  unsigned short* Blo = (unsigned short*)ws; ws += 65536 * sizeof(unsigned short);
  unsigned short* Bmu = (unsigned short*)ws; ws += 4096 * sizeof(unsigned short);

  hipMemsetAsync(accum, 0, (size_t)5 * NB * sizeof(float), stream);
  returns_kernel<<<(NRET * NB + 255) / 256, 256, 0, stream>>>(inp, pert, ret);
  keys_kernel<<<(NSAMP * NSTEP + 255) / 256, 256, 0, stream>>>(keys);
  pack_kernel<<<(65536 + 4096) / 256, 256, 0, stream>>>(W_hh, w_mu, w_ls, Bhi, Blo, Bmu);
  lstm_kernel<false><<<NB / 64, 256, 0, stream>>>(ret, W_ih, bias, Bhi, Blo, Bmu,
      nullptr, nullptr, hh, cc, b_mu, b_ls, keys, nullptr);
  lstm_kernel<true><<<NSAMP * (NB / 64), 256, 0, stream>>>(ret, W_ih, bias, Bhi, Blo, Bmu,
      hh, cc, nullptr, nullptr, b_mu, b_ls, keys, accum);
  final_kernel<<<NB / 256, 256, 0, stream>>>(accum, (float*)d_out);
}

// Round 6
// 14939.713 us; speedup vs baseline: 2.3700x; 1.2556x over previous
//
#include <hip/hip_runtime.h>
#include <stdint.h>
#include <math.h>

// ---------------------------------------------------------------------------
// Round 6: R5 algorithm (split-bf16 MFMA 32x32x16 LSTM, double-buffered h in
// LDS A-frag layout, B pre-split in global/L2), with the register budget
// fixed: __launch_bounds__(256, 1) gives 512 unified regs/thread, so the
// ~220-reg working set (128 AGPR acc + c 32 + frags + addr) fits with ZERO
// spills. R5 still spilled ~11 regs under (256,2) -> 2.9 GB scratch writes
// that (a) sat on the vmcnt critical path and (b) evicted the 256 KB
// B-table from L2 (19.6 GB HBM fetch). Occupancy drops to 1 block/CU
// (1 wave/SIMD); compensated with ILP: kb loop unroll 2 (one-deep B
// prefetch), term-major MFMA order (7-inst gap between same-acc MFMAs),
// t-loop kept rolled to avoid 20x body replication.
// ---------------------------------------------------------------------------

#define HH     128
#define NG     512
#define NB     8192
#define NSAMP  100
#define NSTEP  20
#define TCAP   18
#define NHIST  126
#define NRET   127

using bfrag = __attribute__((ext_vector_type(8))) short;   // 8 bf16 = 4 VGPRs
using facc  = __attribute__((ext_vector_type(16))) float;  // 16 f32 acc

// ----------------------------- threefry2x32 --------------------------------
__device__ __forceinline__ void tf2x32(uint32_t k0, uint32_t k1,
                                       uint32_t x0, uint32_t x1,
                                       uint32_t &y0, uint32_t &y1) {
  uint32_t ks2 = k0 ^ k1 ^ 0x1BD11BDAu;
  x0 += k0; x1 += k1;
#define RR(r) { x0 += x1; x1 = (x1 << (r)) | (x1 >> (32 - (r))); x1 ^= x0; }
  RR(13) RR(15) RR(26) RR(6)   x0 += k1;  x1 += ks2 + 1u;
  RR(17) RR(29) RR(16) RR(24)  x0 += ks2; x1 += k0  + 2u;
  RR(13) RR(15) RR(26) RR(6)   x0 += k0;  x1 += k1  + 3u;
  RR(17) RR(29) RR(16) RR(24)  x0 += k1;  x1 += ks2 + 4u;
  RR(13) RR(15) RR(26) RR(6)   x0 += ks2; x1 += k0  + 5u;
#undef RR
  y0 = x0; y1 = x1;
}

__device__ __forceinline__ float erfinv32(float x) {
  float w = -log1pf(-x * x);
  float p;
  if (w < 5.0f) {
    w = w - 2.5f;
    p = 2.81022636e-08f;
    p = fmaf(p, w, 3.43273939e-07f);
    p = fmaf(p, w, -3.5233877e-06f);
    p = fmaf(p, w, -4.39150654e-06f);
    p = fmaf(p, w, 0.00021858087f);
    p = fmaf(p, w, -0.00125372503f);
    p = fmaf(p, w, -0.00417768164f);
    p = fmaf(p, w, 0.246640727f);
    p = fmaf(p, w, 1.50140941f);
  } else {
    w = sqrtf(w) - 3.0f;
    p = -0.000200214257f;
    p = fmaf(p, w, 0.000100950558f);
    p = fmaf(p, w, 0.00134934322f);
    p = fmaf(p, w, -0.00367342844f);
    p = fmaf(p, w, 0.00573950773f);
    p = fmaf(p, w, -0.0076224613f);
    p = fmaf(p, w, 0.00943887047f);
    p = fmaf(p, w, 1.00167406f);
    p = fmaf(p, w, 2.83297682f);
  }
  return p * x;
}

__device__ __forceinline__ float normal32(uint32_t k0, uint32_t k1, uint32_t idx) {
  uint32_t y0, y1;
  tf2x32(k0, k1, 0u, idx, y0, y1);
  uint32_t bits = y0 ^ y1;
  float f = __uint_as_float((bits >> 9) | 0x3f800000u) - 1.0f;
  const float lo = __uint_as_float(0xBF7FFFFFu);
  float u = fmaxf(lo, f * 2.0f + lo);
  return 1.41421356f * erfinv32(u);
}

__device__ __forceinline__ float fast_sigmoid(float x) {
  return __builtin_amdgcn_rcpf(1.0f + __expf(-x));
}
__device__ __forceinline__ float fast_tanh(float x) {
  return 1.0f - 2.0f * __builtin_amdgcn_rcpf(1.0f + __expf(2.0f * x));
}

// bf16 split helpers (RNE)
__device__ __forceinline__ unsigned short f2bf(float x) {
  uint32_t u = __float_as_uint(x);
  uint32_t r = u + 0x7fffu + ((u >> 16) & 1u);
  return (unsigned short)(r >> 16);
}
__device__ __forceinline__ float bf2f(unsigned short h) {
  return __uint_as_float(((uint32_t)h) << 16);
}

// ------------------------------- small kernels -----------------------------
__global__ void returns_kernel(const float* __restrict__ inp,
                               const float* __restrict__ pert,
                               float* __restrict__ ret) {
  int i = blockIdx.x * blockDim.x + threadIdx.x;
  if (i >= NRET * NB) return;
  int s = i / NB, b = i - s * NB;
  float p0 = inp[s * NB + b] * (1.0f + pert[s * NB + b]);
  float p1 = inp[(s + 1) * NB + b] * (1.0f + pert[(s + 1) * NB + b]);
  ret[i] = p1 - p0;
}

__global__ void keys_kernel(uint32_t* __restrict__ keys) {
  int id = blockIdx.x * blockDim.x + threadIdx.x;
  if (id >= NSAMP * NSTEP) return;
  int s = id / NSTEP, t = id - s * NSTEP;
  uint32_t sk0, sk1, k0, k1;
  tf2x32(0u, 42u, 0u, (uint32_t)s, sk0, sk1);
  tf2x32(sk0, sk1, 0u, (uint32_t)t, k0, k1);
  keys[2 * id] = k0; keys[2 * id + 1] = k1;
}

// Pre-split W_hh into B-fragment layout: Bhi/Blo[((gct*8+kb)*64+lane)*8+j]
//   k = kb*16 + 8*(lane>>5) + j, g = 32*gct + (lane&31).
// Bmu[(kb*64+lane)*8+j]: col0 = w_mu, col1 = w_ls, else 0 (hi only).
__global__ void pack_kernel(const float* __restrict__ W_hh,
                            const float* __restrict__ w_mu,
                            const float* __restrict__ w_ls,
                            unsigned short* __restrict__ Bhi,
                            unsigned short* __restrict__ Blo,
                            unsigned short* __restrict__ Bmu) {
  int idx = blockIdx.x * blockDim.x + threadIdx.x;
  if (idx < 65536) {
    int j = idx & 7, lane = (idx >> 3) & 63, kb = (idx >> 9) & 7, gct = idx >> 12;
    int k = kb * 16 + ((lane >> 5) << 3) + j;
    int g = (gct << 5) + (lane & 31);
    float w = W_hh[k * NG + g];
    unsigned short hi = f2bf(w);
    unsigned short lo = f2bf(w - bf2f(hi));
    Bhi[idx] = hi; Blo[idx] = lo;
  } else if (idx < 65536 + 4096) {
    int i2 = idx - 65536;
    int j = i2 & 7, lane = (i2 >> 3) & 63, kb = (i2 >> 9) & 7;
    int k = kb * 16 + ((lane >> 5) << 3) + j;
    int col = lane & 31;
    float v = (col == 0) ? w_mu[k] : (col == 1 ? w_ls[k] : 0.0f);
    Bmu[i2] = f2bf(v);
  }
}

// ------------------------------ main LSTM kernel ---------------------------
// 64 rows/block, 256 threads = 4 waves; wave cg owns hidden cols 32cg..+31
// across gates i,f,g,o => 8 MFMA tiles (2 row-tiles x 4 gates).
template<bool STOCH>
__launch_bounds__(256, 1)   // 512-reg budget: zero spills (R5 spilled ~11 regs)
__global__ void lstm_kernel(const float* __restrict__ ret,
                            const float* __restrict__ W_ih,
                            const float* __restrict__ bias,
                            const unsigned short* __restrict__ Bhi,
                            const unsigned short* __restrict__ Blo,
                            const unsigned short* __restrict__ Bmu,
                            const float* __restrict__ hin,
                            const float* __restrict__ cin,
                            float* __restrict__ hout,
                            float* __restrict__ cout,
                            const float* __restrict__ b_mu,
                            const float* __restrict__ b_ls,
                            const uint32_t* __restrict__ keys,
                            float* __restrict__ accum) {
  __shared__ unsigned short hfh[2][2][4096];  // [buf][rt][kb*512 + lane*8 + j]
  __shared__ unsigned short hfl[2][2][4096];
  __shared__ float x_s[64];
  __shared__ float mu_s[64];
  __shared__ float ls_s[64];

  const int tid  = threadIdx.x;
  const int lane = tid & 63;
  const int cg   = tid >> 6;          // wave id = hidden-col group
  const int hs   = lane >> 5;         // half-wave (k/row-half selector)
  const int col  = (cg << 5) + (lane & 31);   // hidden col owned in epilogue

  int s, b0;
  if (STOCH) { s = blockIdx.x >> 7; b0 = (blockIdx.x & 127) << 6; }
  else       { s = 0;               b0 = blockIdx.x << 6; }

  // per-lane W_ih / bias for the 4 gates at this hidden col (fp32 exact)
  float wih_r[4], bb_r[4];
#pragma unroll
  for (int gi = 0; gi < 4; ++gi) {
    wih_r[gi] = W_ih[(gi << 7) + col];
    bb_r[gi]  = bias[(gi << 7) + col];
  }
  const float bmu = b_mu[0], bls = b_ls[0];

  // epilogue frag-write offset for this lane's column (row32*8 added later)
  const int coff = (col >> 4) * 512 + ((col >> 3) & 1) * 256 + (col & 7);

  // ---- init h frags (buf 0) + c registers
  float c_reg[2][16];
#pragma unroll
  for (int rt = 0; rt < 2; ++rt) {
#pragma unroll
    for (int reg = 0; reg < 16; ++reg) {
      int row32 = (reg & 3) + ((reg >> 2) << 3) + (hs << 2);
      float hv = 0.0f, cv = 0.0f;
      if (STOCH) {
        int grow = b0 + (rt << 5) + row32;
        hv = hin[grow * HH + col];
        cv = cin[grow * HH + col];
      }
      c_reg[rt][reg] = cv;
      unsigned short hi = f2bf(hv);
      unsigned short lo = f2bf(hv - bf2f(hi));
      hfh[0][rt][coff + row32 * 8] = hi;
      hfl[0][rt][coff + row32 * 8] = lo;
    }
  }
  if (STOCH && tid < 64) x_s[tid] = ret[126 * NB + b0 + tid];
  float logw = 0.0f, outv = 0.0f;
  __syncthreads();

  const int nsteps = STOCH ? NSTEP : NHIST;
  int buf = 0;
#pragma unroll 1
  for (int t = 0; t < nsteps; ++t) {
    const int nbuf = buf ^ 1;

    // ---- C init: x*W_ih + b (fp32 exact)
    facc acc[8];
#pragma unroll
    for (int rt = 0; rt < 2; ++rt) {
#pragma unroll
      for (int reg = 0; reg < 16; ++reg) {
        int row32 = (reg & 3) + ((reg >> 2) << 3) + (hs << 2);
        float xv;
        if (STOCH) xv = x_s[(rt << 5) + row32];
        else       xv = ret[t * NB + b0 + (rt << 5) + row32];
#pragma unroll
        for (int gi = 0; gi < 4; ++gi)
          acc[gi * 2 + rt][reg] = fmaf(xv, wih_r[gi], bb_r[gi]);
      }
    }

    // ---- gate matmul: 3-term split-bf16, 192 MFMAs/wave.
    // unroll 2: one-deep B prefetch across kb (16 B-frags live, ~64 VGPRs —
    // affordable at the 512-reg budget). Term-major MFMA order gives a
    // 7-instruction gap between same-acc-tile MFMAs.
#pragma unroll 2
    for (int kb = 0; kb < 8; ++kb) {
      bfrag ah0 = *(const bfrag*)&hfh[buf][0][kb * 512 + lane * 8];
      bfrag ah1 = *(const bfrag*)&hfh[buf][1][kb * 512 + lane * 8];
      bfrag al0 = *(const bfrag*)&hfl[buf][0][kb * 512 + lane * 8];
      bfrag al1 = *(const bfrag*)&hfl[buf][1][kb * 512 + lane * 8];
      bfrag bh[4], bl[4];
#pragma unroll
      for (int gi = 0; gi < 4; ++gi) {
        const int off = ((((gi << 2) + cg) << 3) + kb) * 512 + lane * 8;
        bh[gi] = *(const bfrag*)&Bhi[off];
        bl[gi] = *(const bfrag*)&Blo[off];
      }
      // term 1: ah * bh   (per acc tile, order stays hh, lh, hl — same math)
#pragma unroll
      for (int gi = 0; gi < 4; ++gi) {
        acc[gi*2+0] = __builtin_amdgcn_mfma_f32_32x32x16_bf16(ah0, bh[gi], acc[gi*2+0], 0, 0, 0);
        acc[gi*2+1] = __builtin_amdgcn_mfma_f32_32x32x16_bf16(ah1, bh[gi], acc[gi*2+1], 0, 0, 0);
      }
      // term 2: al * bh
#pragma unroll
      for (int gi = 0; gi < 4; ++gi) {
        acc[gi*2+0] = __builtin_amdgcn_mfma_f32_32x32x16_bf16(al0, bh[gi], acc[gi*2+0], 0, 0, 0);
        acc[gi*2+1] = __builtin_amdgcn_mfma_f32_32x32x16_bf16(al1, bh[gi], acc[gi*2+1], 0, 0, 0);
      }
      // term 3: ah * bl
#pragma unroll
      for (int gi = 0; gi < 4; ++gi) {
        acc[gi*2+0] = __builtin_amdgcn_mfma_f32_32x32x16_bf16(ah0, bl[gi], acc[gi*2+0], 0, 0, 0);
        acc[gi*2+1] = __builtin_amdgcn_mfma_f32_32x32x16_bf16(ah1, bl[gi], acc[gi*2+1], 0, 0, 0);
      }
    }

    // ---- epilogue: cell update in C-layout regs, write h frags to nbuf
#pragma unroll
    for (int rt = 0; rt < 2; ++rt) {
#pragma unroll
      for (int reg = 0; reg < 16; ++reg) {
        int row32 = (reg & 3) + ((reg >> 2) << 3) + (hs << 2);
        float ig = fast_sigmoid(acc[0 * 2 + rt][reg]);
        float fg = fast_sigmoid(acc[1 * 2 + rt][reg]);
        float gg = fast_tanh  (acc[2 * 2 + rt][reg]);
        float og = fast_sigmoid(acc[3 * 2 + rt][reg]);
        float c  = fmaf(fg, c_reg[rt][reg], ig * gg);
        c_reg[rt][reg] = c;
        float h  = og * fast_tanh(c);
        unsigned short hi = f2bf(h);
        unsigned short lo = f2bf(h - bf2f(hi));
        hfh[nbuf][rt][coff + row32 * 8] = hi;
        hfl[nbuf][rt][coff + row32 * 8] = lo;
        if (!STOCH && t == NHIST - 1)
          hout[(b0 + (rt << 5) + row32) * HH + col] = h;
      }
    }
    __syncthreads();   // B1: new h frags visible (also guards old-buf reuse)

    if (STOCH) {
      if (tid < 64) {   // wave 0: mu/ls MFMA + RNG + x update
        facc am[2];
#pragma unroll
        for (int rt = 0; rt < 2; ++rt)
#pragma unroll
          for (int e = 0; e < 16; ++e) am[rt][e] = 0.0f;
#pragma unroll 1
        for (int kb = 0; kb < 8; ++kb) {
          const bfrag bm = *(const bfrag*)&Bmu[kb * 512 + lane * 8];
          const bfrag a0 = *(const bfrag*)&hfh[nbuf][0][kb * 512 + lane * 8];
          const bfrag a1 = *(const bfrag*)&hfh[nbuf][1][kb * 512 + lane * 8];
          am[0] = __builtin_amdgcn_mfma_f32_32x32x16_bf16(a0, bm, am[0], 0, 0, 0);
          am[1] = __builtin_amdgcn_mfma_f32_32x32x16_bf16(a1, bm, am[1], 0, 0, 0);
        }
        if ((lane & 31) < 2) {
          float* dst = ((lane & 31) == 0) ? mu_s : ls_s;
#pragma unroll
          for (int rt = 0; rt < 2; ++rt)
#pragma unroll
            for (int reg = 0; reg < 16; ++reg)
              dst[(rt << 5) + (reg & 3) + ((reg >> 2) << 3) + (hs << 2)] = am[rt][reg];
        }
        // same-wave LDS RAW: compiler inserts lgkmcnt wait
        float mu  = mu_s[lane] + bmu;
        float lsc = fminf(fmaxf(ls_s[lane] + bls, -5.0f), 2.0f);
        float sg  = __expf(lsc);
        uint32_t k0 = keys[2 * (s * NSTEP + t)];
        uint32_t k1 = keys[2 * (s * NSTEP + t) + 1];
        float z  = normal32(k0, k1, (uint32_t)(b0 + lane));
        float xn = fmaf(sg, z + 0.5f, mu);
        logw -= fmaf(0.5f, z, 0.125f);
        if (t == TCAP) outv = xn;
        x_s[lane] = xn;
      }
      __syncthreads();  // B2: x_s ready
    }
    buf = nbuf;
  }

  if (STOCH) {
    if (tid < 64) {
      float w  = __expf(logw);
      float ow = outv * w;
      int b = b0 + tid;
      atomicAdd(&accum[0 * NB + b], w);
      atomicAdd(&accum[1 * NB + b], ow);
      atomicAdd(&accum[2 * NB + b], w * w);
      atomicAdd(&accum[3 * NB + b], ow * ow);
      atomicAdd(&accum[4 * NB + b], outv * w * w);
    }
  } else {
#pragma unroll
    for (int rt = 0; rt < 2; ++rt)
#pragma unroll
      for (int reg = 0; reg < 16; ++reg) {
        int row32 = (reg & 3) + ((reg >> 2) << 3) + (hs << 2);
        cout[(b0 + (rt << 5) + row32) * HH + col] = c_reg[rt][reg];
      }
  }
}

// ------------------------------- final kernel ------------------------------
__global__ void final_kernel(const float* __restrict__ accum,
                             float* __restrict__ out) {
  int b = blockIdx.x * blockDim.x + threadIdx.x;
  if (b >= NB) return;
  float sw  = accum[0 * NB + b];
  float sm1 = accum[1 * NB + b];
  float sqw = accum[2 * NB + b];
  float sm2 = accum[3 * NB + b];
  float shm = accum[4 * NB + b];
  float mean = sm1 / sw;
  float sem = sm2 + sqw * mean * mean - 2.0f * shm * mean;
  sem = sqrtf(sem / (float)(NSAMP * (NSAMP - 1)));
  out[b] = mean;
  out[NB + b] = sem;
}

// ------------------------------- launcher ----------------------------------
extern "C" void kernel_launch(void* const* d_in, const int* in_sizes, int n_in,
                              void* d_out, int out_size, void* d_ws, size_t ws_size,
                              hipStream_t stream) {
  (void)in_sizes; (void)n_in; (void)out_size; (void)ws_size;
  const float* inp  = (const float*)d_in[0];
  const float* pert = (const float*)d_in[1];
  const float* W_ih = (const float*)d_in[2];
  const float* W_hh = (const float*)d_in[3];
  const float* bias = (const float*)d_in[4];
  const float* w_mu = (const float*)d_in[5];
  const float* b_mu = (const float*)d_in[6];
  const float* w_ls = (const float*)d_in[7];
  const float* b_ls = (const float*)d_in[8];

  char* ws = (char*)d_ws;
  float* ret = (float*)ws;        ws += (size_t)NRET * NB * sizeof(float);
  float* hh  = (float*)ws;        ws += (size_t)NB * HH * sizeof(float);
  float* cc  = (float*)ws;        ws += (size_t)NB * HH * sizeof(float);
  uint32_t* keys = (uint32_t*)ws; ws += (size_t)NSAMP * NSTEP * 2 * sizeof(uint32_t);
  float* accum = (float*)ws;      ws += (size_t)5 * NB * sizeof(float);
  unsigned short* Bhi = (unsigned short*)ws; ws += 65536 * sizeof(unsigned short);
  unsigned short* Blo = (unsigned short*)ws; ws += 65536 * sizeof(unsigned short);
  unsigned short* Bmu = (unsigned short*)ws; ws += 4096 * sizeof(unsigned short);

  hipMemsetAsync(accum, 0, (size_t)5 * NB * sizeof(float), stream);
  returns_kernel<<<(NRET * NB + 255) / 256, 256, 0, stream>>>(inp, pert, ret);
  keys_kernel<<<(NSAMP * NSTEP + 255) / 256, 256, 0, stream>>>(keys);
  pack_kernel<<<(65536 + 4096) / 256, 256, 0, stream>>>(W_hh, w_mu, w_ls, Bhi, Blo, Bmu);
  lstm_kernel<false><<<NB / 64, 256, 0, stream>>>(ret, W_ih, bias, Bhi, Blo, Bmu,
      nullptr, nullptr, hh, cc, b_mu, b_ls, keys, nullptr);
  lstm_kernel<true><<<NSAMP * (NB / 64), 256, 0, stream>>>(ret, W_ih, bias, Bhi, Blo, Bmu,
      hh, cc, nullptr, nullptr, b_mu, b_ls, keys, accum);
  final_kernel<<<NB / 256, 256, 0, stream>>>(accum, (float*)d_out);
}